// Round 9
// baseline (4154.175 us; speedup 1.0000x reference)
//
#include <hip/hip_runtime.h>
#include <math.h>

#define NRAYS 262144
#define MAXIT 192
#define NEARV 0.2f
#define FARV  2.0f
#define EPSV  0.001f
#define KCHUNK 16
#define NROUNDS 12   // KCHUNK * NROUNDS == MAXIT

// ---------------------------------------------------------------------------
// Single-ray SDF MLP eval (fallback path only) — canonical fma order,
// scalar weight loads.
// ---------------------------------------------------------------------------
__device__ __forceinline__ float sdf_eval(
    float px, float py, float pz,
    const float* __restrict__ W0, const float* __restrict__ b0,
    const float* __restrict__ W1, const float* __restrict__ b1,
    const float* __restrict__ W2, float b2_0)
{
    float h1[64];
    #pragma unroll
    for (int j = 0; j < 64; ++j) h1[j] = 0.f;

    for (int k = 0; k < 64; ++k) {
        float z = px * W0[k] + py * W0[64 + k] + pz * W0[128 + k];
        z += b0[k];
        const float a = fmaxf(z, 0.f);
        #pragma unroll
        for (int j = 0; j < 64; ++j) h1[j] = fmaf(a, W1[k * 64 + j], h1[j]);
    }

    float d = 0.f;
    #pragma unroll
    for (int j = 0; j < 64; ++j)
        d = fmaf(fmaxf(h1[j] + b1[j], 0.f), W2[j * 33], d);
    return d + b2_0;
}

// ---------------------------------------------------------------------------
// Round-based march: 2 rays/lane + phase-lock, 512-reg unified budget.
// Model closed in R8: per k-row, exposed s_load latency S~4700cyc/step is
// FIXED (SGPR budget 102 can't double-buffer a 64-SGPR row); VALU issue
// I~9344cyc/step -> busy = I/(I+S) = 67% (measured 66.7%). Doubling math
// per row (2 rays/lane) halves S's share: (2I+S)/(2(I+S)) = 0.83.
// R4's dual-ray failed PRE-phase-lock (S scaled with math when waves
// thrashed K$ at uncorrelated phases); R6/R8 proved the s_barrier clamp
// fixes that. 256-thread blocks keep blocks = n/512 (same tail-round
// parallelism as R8). (256,1): 512-reg budget, accumulator/budget ratio
// 128/512 = R8's proven-single-pass 64/256.
// Per-ray fma chains identical to sdf_eval (R4's verified interleave)
// -> bit-identical t/hit.
// ---------------------------------------------------------------------------
__global__ __launch_bounds__(256, 1)
void march_round2(const float* __restrict__ rays,
                  const float* __restrict__ W0, const float* __restrict__ b0,
                  const float* __restrict__ W1, const float* __restrict__ b1,
                  const float* __restrict__ W2, const float* __restrict__ b2,
                  int round0, int it_base,
                  const int* __restrict__ in_cnt,
                  const int* __restrict__ in_idx, const float* __restrict__ in_cd,
                  int* __restrict__ out_cnt,
                  int* __restrict__ out_idx, float* __restrict__ out_cd,
                  float* __restrict__ t_out,
                  int* __restrict__ hitq, int* __restrict__ hit_cnt)
{
    const int i    = blockIdx.x * 256 + threadIdx.x;   // pair index
    const int lane = threadIdx.x & 63;
    const int n    = round0 ? NRAYS : *in_cnt;

    // Block-uniform early exit BEFORE any barrier (empty tail blocks).
    if (blockIdx.x * 512 >= n) return;

    const int sA = 2 * i, sB = 2 * i + 1;
    bool aliveA = (sA < n), aliveB = (sB < n);
    bool hitA = false, hitB = false;
    int  ridxA = 0, ridxB = 0;
    float cdA = NEARV, cdB = NEARV;
    int  itA = it_base, itB = it_base;

    if (aliveA) {
        if (round0) { ridxA = sA; } else { ridxA = in_idx[sA]; cdA = in_cd[sA]; }
    }
    if (aliveB) {
        if (round0) { ridxB = sB; } else { ridxB = in_idx[sB]; cdB = in_cd[sB]; }
    }

    const float* rA = rays + (size_t)ridxA * 6;   // dead slots read ray 0
    const float oxA = rA[0], oyA = rA[1], ozA = rA[2];
    const float rdxA = rA[3], rdyA = rA[4], rdzA = rA[5];
    const float* rB = rays + (size_t)ridxB * 6;
    const float oxB = rB[0], oyB = rB[1], ozB = rB[2];
    const float rdxB = rB[3], rdyB = rB[4], rdzB = rB[5];
    const float b2_0 = b2[0];

    // Fixed trip count: every wave executes every barrier.
    for (int s = 0; s < KCHUNK; ++s) {
        const float pxA = oxA + rdxA * cdA;
        const float pyA = oyA + rdyA * cdA;
        const float pzA = ozA + rdzA * cdA;
        const float pxB = oxB + rdxB * cdB;
        const float pyB = oyB + rdyB * cdB;
        const float pzB = ozB + rdzB * cdB;

        float hA[64], hB[64];
        #pragma unroll
        for (int j = 0; j < 64; ++j) { hA[j] = 0.f; hB[j] = 0.f; }

        for (int kt = 0; kt < 8; ++kt) {
            #pragma unroll
            for (int kk = 0; kk < 8; ++kk) {
                const int k = kt * 8 + kk;
                float zA = pxA * W0[k] + pyA * W0[64 + k] + pzA * W0[128 + k];
                zA += b0[k];
                float zB = pxB * W0[k] + pyB * W0[64 + k] + pzB * W0[128 + k];
                zB += b0[k];
                const float aA = fmaxf(zA, 0.f);
                const float aB = fmaxf(zB, 0.f);
                const float* __restrict__ wr = W1 + k * 64;
                #pragma unroll
                for (int j = 0; j < 64; ++j) {
                    const float w = wr[j];
                    hA[j] = fmaf(aA, w, hA[j]);
                    hB[j] = fmaf(aB, w, hB[j]);
                }
            }
            // Phase clamp only. No data crosses this barrier, so no
            // s_waitcnt drain (raw s_barrier, not __syncthreads).
            __builtin_amdgcn_s_barrier();
        }

        float dA = 0.f, dB = 0.f;
        #pragma unroll
        for (int j = 0; j < 64; ++j) {
            const float b = b1[j];
            const float w = W2[j * 33];
            dA = fmaf(fmaxf(hA[j] + b, 0.f), w, dA);
            dB = fmaf(fmaxf(hB[j] + b, 0.f), w, dB);
        }
        dA += b2_0;
        dB += b2_0;

        if (aliveA) {
            ++itA;
            if (dA < EPSV && cdA <= FARV) hitA = true;
            cdA += dA;
            if (hitA || cdA > FARV || itA >= MAXIT) {
                t_out[ridxA] = cdA;
                if (hitA) { const int p = atomicAdd(hit_cnt, 1); hitq[p] = ridxA; }
                aliveA = false;
            }
        }
        if (aliveB) {
            ++itB;
            if (dB < EPSV && cdB <= FARV) hitB = true;
            cdB += dB;
            if (hitB || cdB > FARV || itB >= MAXIT) {
                t_out[ridxB] = cdB;
                if (hitB) { const int p = atomicAdd(hit_cnt, 1); hitq[p] = ridxB; }
                aliveB = false;
            }
        }
    }

    // Wave-aggregated compaction of survivors (slot A then slot B).
    unsigned long long m = __ballot(aliveA);
    if (m != 0ull) {
        const int leader = __builtin_ctzll(m);
        int base = 0;
        if (lane == leader) base = atomicAdd(out_cnt, __builtin_popcountll(m));
        base = __shfl(base, leader);
        if (aliveA) {
            const int off = __builtin_popcountll(m & ((1ull << lane) - 1ull));
            out_idx[base + off] = ridxA;
            out_cd[base + off]  = cdA;
        }
    }
    m = __ballot(aliveB);
    if (m != 0ull) {
        const int leader = __builtin_ctzll(m);
        int base = 0;
        if (lane == leader) base = atomicAdd(out_cnt, __builtin_popcountll(m));
        base = __shfl(base, leader);
        if (aliveB) {
            const int off = __builtin_popcountll(m & ((1ull << lane) - 1ull));
            out_idx[base + off] = ridxB;
            out_cd[base + off]  = cdB;
        }
    }
}

// ---------------------------------------------------------------------------
// Shade only the hit rays (dense hit queue). Output memset to zero.
// Bit-identical arithmetic to the passing shade kernel.
// ---------------------------------------------------------------------------
__global__ __launch_bounds__(256, 2)
void shade_hit(const float* __restrict__ rays,
               const float* __restrict__ W0, const float* __restrict__ b0,
               const float* __restrict__ W1, const float* __restrict__ b1,
               const float* __restrict__ W2, const float* __restrict__ b2,
               const float* __restrict__ RW0, const float* __restrict__ Rb0,
               const float* __restrict__ RW1, const float* __restrict__ Rb1,
               const float* __restrict__ t_in,
               const int* __restrict__ hitq, const int* __restrict__ hit_cnt,
               float* __restrict__ out)
{
    const int n = *hit_cnt;
    if (blockIdx.x * 256 >= n) return;   // whole block empty -> skip staging

    __shared__ float sW0[3 * 64];
    __shared__ float sb0[64];
    __shared__ float sW1[64 * 64];
    __shared__ float sb1[64];
    __shared__ float sW2T[33 * 64];   // [c][j] = W2[j][c]
    __shared__ float sb2[33];
    __shared__ float sRW0T[64 * 48];  // [u][f] = RW0[f][u], padded 41->48
    __shared__ float sRb0[64];
    __shared__ float sRW1[64 * 3];
    __shared__ float sRb1[3];

    const int tid = threadIdx.x;
    for (int i = tid; i < 3 * 64; i += 256) sW0[i] = W0[i];
    for (int i = tid; i < 64 * 64; i += 256) sW1[i] = W1[i];
    for (int i = tid; i < 33 * 64; i += 256) {
        const int c = i >> 6, j = i & 63;
        sW2T[i] = W2[j * 33 + c];
    }
    for (int i = tid; i < 64 * 41; i += 256) {
        const int u = i / 41, f = i - u * 41;
        sRW0T[u * 48 + f] = RW0[f * 64 + u];
    }
    if (tid < 64) { sb0[tid] = b0[tid]; sb1[tid] = b1[tid]; sRb0[tid] = Rb0[tid]; }
    if (tid < 33) sb2[tid] = b2[tid];
    if (tid < 192) sRW1[tid] = RW1[tid];
    if (tid < 3) sRb1[tid] = Rb1[tid];
    __syncthreads();

    const int qi = blockIdx.x * 256 + tid;
    if (qi >= n) return;
    const int i = hitq[qi];

    const float* r = rays + (size_t)i * 6;
    const float cd = t_in[i];
    const float ox = r[0], oy = r[1], oz = r[2];
    const float dx = r[3], dy = r[4], dz = r[5];
    const float px = ox + dx * cd;
    const float py = oy + dy * cd;
    const float pz = oz + dz * cd;

    // ---- forward, layer 1 accumulation ----
    float h1[64];
    #pragma unroll
    for (int j = 0; j < 64; ++j) h1[j] = 0.f;

    for (int k = 0; k < 64; ++k) {
        float z = px * sW0[k] + py * sW0[64 + k] + pz * sW0[128 + k];
        z += sb0[k];
        const float a = fmaxf(z, 0.f);
        #pragma unroll
        for (int j = 0; j < 64; ++j) h1[j] = fmaf(a, sW1[k * 64 + j], h1[j]);
    }
    #pragma unroll
    for (int j = 0; j < 64; ++j) h1[j] = fmaxf(h1[j] + sb1[j], 0.f);

    // ---- latent = out[:,1:33] ----
    float lat[32];
    #pragma unroll
    for (int c = 1; c < 33; ++c) {
        float acc = 0.f;
        #pragma unroll
        for (int j = 0; j < 64; ++j) acc = fmaf(h1[j], sW2T[c * 64 + j], acc);
        lat[c - 1] = acc + sb2[c];
    }

    // ---- backward: gz1 = (z1>0) ? W2[:,0] : 0 ----
    #pragma unroll
    for (int j = 0; j < 64; ++j) h1[j] = (h1[j] > 0.f) ? sW2T[j] : 0.f;

    float nx = 0.f, ny = 0.f, nz = 0.f;
    for (int k = 0; k < 64; ++k) {
        float z = px * sW0[k] + py * sW0[64 + k] + pz * sW0[128 + k];
        z += sb0[k];
        float g = 0.f;
        #pragma unroll
        for (int j = 0; j < 64; ++j) g = fmaf(h1[j], sW1[k * 64 + j], g);
        if (z > 0.f) {
            nx = fmaf(g, sW0[k], nx);
            ny = fmaf(g, sW0[64 + k], ny);
            nz = fmaf(g, sW0[128 + k], nz);
        }
    }

    // ---- render MLP: feat(41) = [pts, r_d, nrm, latent] ----
    float r0 = 0.f, r1 = 0.f, r2 = 0.f;
    for (int u = 0; u < 64; ++u) {
        const float* w = &sRW0T[u * 48];
        float a = px * w[0] + py * w[1] + pz * w[2];
        a = fmaf(dx, w[3], a); a = fmaf(dy, w[4], a); a = fmaf(dz, w[5], a);
        a = fmaf(nx, w[6], a); a = fmaf(ny, w[7], a); a = fmaf(nz, w[8], a);
        #pragma unroll
        for (int q = 0; q < 32; ++q) a = fmaf(lat[q], w[9 + q], a);
        a += sRb0[u];
        const float ru = fmaxf(a, 0.f);
        r0 = fmaf(ru, sRW1[u * 3 + 0], r0);
        r1 = fmaf(ru, sRW1[u * 3 + 1], r1);
        r2 = fmaf(ru, sRW1[u * 3 + 2], r2);
    }
    r0 += sRb1[0]; r1 += sRb1[1]; r2 += sRb1[2];

    out[i * 3 + 0] = 1.f / (1.f + expf(-r0));
    out[i * 3 + 1] = 1.f / (1.f + expf(-r1));
    out[i * 3 + 2] = 1.f / (1.f + expf(-r2));
}

// ---------------------------------------------------------------------------
// Fallback path (only if workspace is too small for the queues).
// ---------------------------------------------------------------------------
__global__ __launch_bounds__(256, 2)
void march_kernel(const float* __restrict__ rays,
                  const float* __restrict__ W0, const float* __restrict__ b0,
                  const float* __restrict__ W1, const float* __restrict__ b1,
                  const float* __restrict__ W2, const float* __restrict__ b2,
                  float* __restrict__ t_out, int* __restrict__ hit_out,
                  int* __restrict__ counter)
{
    float ox = 0.f, oy = 0.f, oz = 0.f, rdx = 0.f, rdy = 0.f, rdz = 0.f;
    float cd = 0.f;
    int ridx = -1, it = 0;
    bool has = false, hit = false, exhausted = false;

    const float b2_0 = b2[0];

    while (true) {
        if (!has && !exhausted) {
            int idx = atomicAdd(counter, 1);
            if (idx < NRAYS) {
                const float* r = rays + (size_t)idx * 6;
                ox = r[0]; oy = r[1]; oz = r[2];
                rdx = r[3]; rdy = r[4]; rdz = r[5];
                cd = NEARV; it = 0; hit = false; has = true; ridx = idx;
            } else {
                exhausted = true;
            }
        }
        if (__ballot(has) == 0ull) break;

        const float px = ox + rdx * cd;
        const float py = oy + rdy * cd;
        const float pz = oz + rdz * cd;

        const float d = sdf_eval(px, py, pz, W0, b0, W1, b1, W2, b2_0);

        if (has) {
            ++it;
            if (d < EPSV && cd <= FARV) hit = true;
            cd += d;
            if (hit || cd > FARV || it >= MAXIT) {
                t_out[ridx] = cd;
                hit_out[ridx] = hit ? 1 : 0;
                has = false;
            }
        }
    }
}

__global__ __launch_bounds__(256, 2)
void shade_kernel(const float* __restrict__ rays,
                  const float* __restrict__ W0, const float* __restrict__ b0,
                  const float* __restrict__ W1, const float* __restrict__ b1,
                  const float* __restrict__ W2, const float* __restrict__ b2,
                  const float* __restrict__ RW0, const float* __restrict__ Rb0,
                  const float* __restrict__ RW1, const float* __restrict__ Rb1,
                  const float* __restrict__ t_in, const int* __restrict__ hit_in,
                  float* __restrict__ out)
{
    __shared__ float sW0[3 * 64];
    __shared__ float sb0[64];
    __shared__ float sW1[64 * 64];
    __shared__ float sb1[64];
    __shared__ float sW2T[33 * 64];
    __shared__ float sb2[33];
    __shared__ float sRW0T[64 * 48];
    __shared__ float sRb0[64];
    __shared__ float sRW1[64 * 3];
    __shared__ float sRb1[3];

    const int tid = threadIdx.x;
    for (int i = tid; i < 3 * 64; i += 256) sW0[i] = W0[i];
    for (int i = tid; i < 64 * 64; i += 256) sW1[i] = W1[i];
    for (int i = tid; i < 33 * 64; i += 256) {
        const int c = i >> 6, j = i & 63;
        sW2T[i] = W2[j * 33 + c];
    }
    for (int i = tid; i < 64 * 41; i += 256) {
        const int u = i / 41, f = i - u * 41;
        sRW0T[u * 48 + f] = RW0[f * 64 + u];
    }
    if (tid < 64) { sb0[tid] = b0[tid]; sb1[tid] = b1[tid]; sRb0[tid] = Rb0[tid]; }
    if (tid < 33) sb2[tid] = b2[tid];
    if (tid < 192) sRW1[tid] = RW1[tid];
    if (tid < 3) sRb1[tid] = Rb1[tid];
    __syncthreads();

    const int i = blockIdx.x * 256 + tid;
    const bool hit = hit_in[i] != 0;

    if (__ballot(hit) == 0ull) {
        out[i * 3 + 0] = 0.f;
        out[i * 3 + 1] = 0.f;
        out[i * 3 + 2] = 0.f;
        return;
    }

    const float* r = rays + (size_t)i * 6;
    const float cd = t_in[i];
    const float ox = r[0], oy = r[1], oz = r[2];
    const float dx = r[3], dy = r[4], dz = r[5];
    const float px = ox + dx * cd;
    const float py = oy + dy * cd;
    const float pz = oz + dz * cd;

    float h1[64];
    #pragma unroll
    for (int j = 0; j < 64; ++j) h1[j] = 0.f;

    for (int k = 0; k < 64; ++k) {
        float z = px * sW0[k] + py * sW0[64 + k] + pz * sW0[128 + k];
        z += sb0[k];
        const float a = fmaxf(z, 0.f);
        #pragma unroll
        for (int j = 0; j < 64; ++j) h1[j] = fmaf(a, sW1[k * 64 + j], h1[j]);
    }
    #pragma unroll
    for (int j = 0; j < 64; ++j) h1[j] = fmaxf(h1[j] + sb1[j], 0.f);

    float lat[32];
    #pragma unroll
    for (int c = 1; c < 33; ++c) {
        float acc = 0.f;
        #pragma unroll
        for (int j = 0; j < 64; ++j) acc = fmaf(h1[j], sW2T[c * 64 + j], acc);
        lat[c - 1] = acc + sb2[c];
    }

    #pragma unroll
    for (int j = 0; j < 64; ++j) h1[j] = (h1[j] > 0.f) ? sW2T[j] : 0.f;

    float nx = 0.f, ny = 0.f, nz = 0.f;
    for (int k = 0; k < 64; ++k) {
        float z = px * sW0[k] + py * sW0[64 + k] + pz * sW0[128 + k];
        z += sb0[k];
        float g = 0.f;
        #pragma unroll
        for (int j = 0; j < 64; ++j) g = fmaf(h1[j], sW1[k * 64 + j], g);
        if (z > 0.f) {
            nx = fmaf(g, sW0[k], nx);
            ny = fmaf(g, sW0[64 + k], ny);
            nz = fmaf(g, sW0[128 + k], nz);
        }
    }
    if (!hit) { nx = 0.f; ny = 0.f; nz = 0.f; }

    float r0 = 0.f, r1 = 0.f, r2 = 0.f;
    for (int u = 0; u < 64; ++u) {
        const float* w = &sRW0T[u * 48];
        float a = px * w[0] + py * w[1] + pz * w[2];
        a = fmaf(dx, w[3], a); a = fmaf(dy, w[4], a); a = fmaf(dz, w[5], a);
        a = fmaf(nx, w[6], a); a = fmaf(ny, w[7], a); a = fmaf(nz, w[8], a);
        #pragma unroll
        for (int q = 0; q < 32; ++q) a = fmaf(lat[q], w[9 + q], a);
        a += sRb0[u];
        const float ru = fmaxf(a, 0.f);
        r0 = fmaf(ru, sRW1[u * 3 + 0], r0);
        r1 = fmaf(ru, sRW1[u * 3 + 1], r1);
        r2 = fmaf(ru, sRW1[u * 3 + 2], r2);
    }
    r0 += sRb1[0]; r1 += sRb1[1]; r2 += sRb1[2];

    const float o0 = 1.f / (1.f + expf(-r0));
    const float o1 = 1.f / (1.f + expf(-r1));
    const float o2 = 1.f / (1.f + expf(-r2));

    out[i * 3 + 0] = hit ? o0 : 0.f;
    out[i * 3 + 1] = hit ? o1 : 0.f;
    out[i * 3 + 2] = hit ? o2 : 0.f;
}

extern "C" void kernel_launch(void* const* d_in, const int* in_sizes, int n_in,
                              void* d_out, int out_size, void* d_ws, size_t ws_size,
                              hipStream_t stream) {
    const float* rays = (const float*)d_in[0];
    const float* W0   = (const float*)d_in[1];
    const float* b0   = (const float*)d_in[2];
    const float* W1   = (const float*)d_in[3];
    const float* b1   = (const float*)d_in[4];
    const float* W2   = (const float*)d_in[5];
    const float* b2   = (const float*)d_in[6];
    const float* RW0  = (const float*)d_in[7];
    const float* Rb0  = (const float*)d_in[8];
    const float* RW1  = (const float*)d_in[9];
    const float* Rb1  = (const float*)d_in[10];

    // Workspace layout (4-byte units):
    //   [0..15]                    counters: cnt[r]=survivors after round r, cnt[15]=hit count
    //   [16          .. 16+N)      t
    //   [16+N        .. 16+2N)     queue A idx
    //   [16+2N       .. 16+3N)     queue A cd
    //   [16+3N       .. 16+4N)     queue B idx
    //   [16+4N       .. 16+5N)     queue B cd
    //   [16+5N       .. 16+6N)     hit queue
    const size_t need = (size_t)(16 + 6 * NRAYS) * 4;

    if (ws_size >= need) {
        int*   cnt  = (int*)d_ws;
        float* t_ws = (float*)d_ws + 16;
        int*   qiA  = (int*)d_ws + 16 + (size_t)NRAYS;
        float* qcA  = (float*)d_ws + 16 + 2 * (size_t)NRAYS;
        int*   qiB  = (int*)d_ws + 16 + 3 * (size_t)NRAYS;
        float* qcB  = (float*)d_ws + 16 + 4 * (size_t)NRAYS;
        int*   hitq = (int*)d_ws + 16 + 5 * (size_t)NRAYS;

        hipMemsetAsync(cnt, 0, 16 * sizeof(int), stream);
        hipMemsetAsync(d_out, 0, (size_t)out_size, stream);

        // 2 rays/lane in 256-thread blocks -> 512 rays/block.
        const int blocks = NRAYS / 512;

        // Round 0: all rays fresh, survivors -> queue A (cnt[0]).
        march_round2<<<blocks, 256, 0, stream>>>(
            rays, W0, b0, W1, b1, W2, b2,
            1, 0, nullptr, nullptr, nullptr,
            &cnt[0], qiA, qcA, t_ws, hitq, &cnt[15]);

        for (int r2 = 1; r2 < NROUNDS; ++r2) {
            const int*   icnt = &cnt[r2 - 1];
            int*         ocnt = &cnt[r2];
            const int*   ii = (r2 & 1) ? qiA : qiB;
            const float* ic = (r2 & 1) ? qcA : qcB;
            int*         oi = (r2 & 1) ? qiB : qiA;
            float*       oc = (r2 & 1) ? qcB : qcA;
            march_round2<<<blocks, 256, 0, stream>>>(
                rays, W0, b0, W1, b1, W2, b2,
                0, r2 * KCHUNK, icnt, ii, ic,
                ocnt, oi, oc, t_ws, hitq, &cnt[15]);
        }

        shade_hit<<<NRAYS / 256, 256, 0, stream>>>(
            rays, W0, b0, W1, b1, W2, b2, RW0, Rb0, RW1, Rb1,
            t_ws, hitq, &cnt[15], (float*)d_out);
    } else {
        // Fallback: previous passing path.
        float* t_ws  = (float*)d_ws;
        int*   hit_ws = (int*)d_ws + NRAYS;
        int*   ctr    = (int*)d_ws + 2 * NRAYS;

        hipMemsetAsync(ctr, 0, sizeof(int), stream);
        march_kernel<<<1024, 256, 0, stream>>>(rays, W0, b0, W1, b1, W2, b2,
                                               t_ws, hit_ws, ctr);
        shade_kernel<<<NRAYS / 256, 256, 0, stream>>>(rays, W0, b0, W1, b1, W2, b2,
                                                      RW0, Rb0, RW1, Rb1,
                                                      t_ws, hit_ws, (float*)d_out);
    }
}

// Round 10
// 3707.986 us; speedup vs baseline: 1.1203x; 1.1203x over previous
//
#include <hip/hip_runtime.h>
#include <math.h>

#define NRAYS 262144
#define MAXIT 192
#define NEARV 0.2f
#define FARV  2.0f
#define EPSV  0.001f
#define MBLK 512      // march block size (8 waves)
#define NROUNDS 16    // schedule: 1,1,2,4,8 then 11x16 = 192 steps

// ---------------------------------------------------------------------------
// Single-ray SDF MLP eval (fallback path only) — canonical fma order,
// scalar weight loads.
// ---------------------------------------------------------------------------
__device__ __forceinline__ float sdf_eval(
    float px, float py, float pz,
    const float* __restrict__ W0, const float* __restrict__ b0,
    const float* __restrict__ W1, const float* __restrict__ b1,
    const float* __restrict__ W2, float b2_0)
{
    float h1[64];
    #pragma unroll
    for (int j = 0; j < 64; ++j) h1[j] = 0.f;

    for (int k = 0; k < 64; ++k) {
        float z = px * W0[k] + py * W0[64 + k] + pz * W0[128 + k];
        z += b0[k];
        const float a = fmaxf(z, 0.f);
        #pragma unroll
        for (int j = 0; j < 64; ++j) h1[j] = fmaf(a, W1[k * 64 + j], h1[j]);
    }

    float d = 0.f;
    #pragma unroll
    for (int j = 0; j < 64; ++j)
        d = fmaf(fmaxf(h1[j] + b1[j], 0.f), W2[j * 33], d);
    return d + b2_0;
}

// ---------------------------------------------------------------------------
// R8 march kernel (best measured: 66.7% VALUBusy, single-pass codegen)
// with a RUNTIME chunk length. Inner loop is bit-identical to R8.
//   - (512,2): 256-reg unified budget -> h1[64] stays single-pass (R8).
//   - raw s_barrier per 8 k's: phase-locks block waves into one K$ window
//     (R6: busy 58.6->73.5%); no data crosses it, no waitcnt drain.
//   - kchunk is now an argument: early rounds use short chunks (1,1,2,4,8)
//     so rays that die at step 1 (~45% of all rays: random-MLP d<EPS
//     coin-flip) stop burning dead steps; creeper rounds use 16.
// fma order identical to sdf_eval -> bit-identical t/hit.
// ---------------------------------------------------------------------------
__global__ __launch_bounds__(MBLK, 2)
void march_round(const float* __restrict__ rays,
                 const float* __restrict__ W0, const float* __restrict__ b0,
                 const float* __restrict__ W1, const float* __restrict__ b1,
                 const float* __restrict__ W2, const float* __restrict__ b2,
                 int round0, int it_base, int kchunk,
                 const int* __restrict__ in_cnt,
                 const int* __restrict__ in_idx, const float* __restrict__ in_cd,
                 int* __restrict__ out_cnt,
                 int* __restrict__ out_idx, float* __restrict__ out_cd,
                 float* __restrict__ t_out,
                 int* __restrict__ hitq, int* __restrict__ hit_cnt)
{
    const int i    = blockIdx.x * MBLK + threadIdx.x;
    const int lane = threadIdx.x & 63;
    const int n    = round0 ? NRAYS : *in_cnt;

    // Block-uniform early exit BEFORE any barrier (empty tail blocks).
    if (blockIdx.x * MBLK >= n) return;

    bool alive = (i < n);
    bool hit   = false;
    int  ridx  = 0;
    float cd   = NEARV;
    int  it    = it_base;

    if (alive) {
        if (round0) {
            ridx = i;
        } else {
            ridx = in_idx[i];
            cd   = in_cd[i];
        }
    }

    const float* r = rays + (size_t)ridx * 6;   // dead lanes read ray 0 (in-bounds)
    const float ox = r[0], oy = r[1], oz = r[2];
    const float rdx = r[3], rdy = r[4], rdz = r[5];
    const float b2_0 = b2[0];

    // Fixed trip count: every wave executes every barrier.
    for (int s = 0; s < kchunk; ++s) {
        const float px = ox + rdx * cd;
        const float py = oy + rdy * cd;
        const float pz = oz + rdz * cd;

        float h1[64];
        #pragma unroll
        for (int j = 0; j < 64; ++j) h1[j] = 0.f;

        for (int kt = 0; kt < 8; ++kt) {
            #pragma unroll
            for (int kk = 0; kk < 8; ++kk) {
                const int k = kt * 8 + kk;
                float z = px * W0[k] + py * W0[64 + k] + pz * W0[128 + k];
                z += b0[k];
                const float a = fmaxf(z, 0.f);
                #pragma unroll
                for (int j = 0; j < 64; ++j)
                    h1[j] = fmaf(a, W1[k * 64 + j], h1[j]);
            }
            // Phase clamp only (raw s_barrier, not __syncthreads).
            __builtin_amdgcn_s_barrier();
        }

        float d = 0.f;
        #pragma unroll
        for (int j = 0; j < 64; ++j)
            d = fmaf(fmaxf(h1[j] + b1[j], 0.f), W2[j * 33], d);
        d += b2_0;

        if (alive) {
            ++it;
            if (d < EPSV && cd <= FARV) hit = true;
            cd += d;
            if (hit || cd > FARV || it >= MAXIT) {
                t_out[ridx] = cd;
                if (hit) {
                    const int p = atomicAdd(hit_cnt, 1);
                    hitq[p] = ridx;
                }
                alive = false;
            }
        }
    }

    // Wave-aggregated compaction of survivors into the out-queue.
    const unsigned long long m = __ballot(alive);
    if (m != 0ull) {
        const int leader = __builtin_ctzll(m);
        int base = 0;
        if (lane == leader) base = atomicAdd(out_cnt, __builtin_popcountll(m));
        base = __shfl(base, leader);
        if (alive) {
            const int off = __builtin_popcountll(m & ((1ull << lane) - 1ull));
            out_idx[base + off] = ridx;
            out_cd[base + off]  = cd;
        }
    }
}

// ---------------------------------------------------------------------------
// Shade only the hit rays (dense hit queue). Output memset to zero.
// Bit-identical arithmetic to the passing shade kernel.
// ---------------------------------------------------------------------------
__global__ __launch_bounds__(256, 2)
void shade_hit(const float* __restrict__ rays,
               const float* __restrict__ W0, const float* __restrict__ b0,
               const float* __restrict__ W1, const float* __restrict__ b1,
               const float* __restrict__ W2, const float* __restrict__ b2,
               const float* __restrict__ RW0, const float* __restrict__ Rb0,
               const float* __restrict__ RW1, const float* __restrict__ Rb1,
               const float* __restrict__ t_in,
               const int* __restrict__ hitq, const int* __restrict__ hit_cnt,
               float* __restrict__ out)
{
    const int n = *hit_cnt;
    if (blockIdx.x * 256 >= n) return;   // whole block empty -> skip staging

    __shared__ float sW0[3 * 64];
    __shared__ float sb0[64];
    __shared__ float sW1[64 * 64];
    __shared__ float sb1[64];
    __shared__ float sW2T[33 * 64];   // [c][j] = W2[j][c]
    __shared__ float sb2[33];
    __shared__ float sRW0T[64 * 48];  // [u][f] = RW0[f][u], padded 41->48
    __shared__ float sRb0[64];
    __shared__ float sRW1[64 * 3];
    __shared__ float sRb1[3];

    const int tid = threadIdx.x;
    for (int i = tid; i < 3 * 64; i += 256) sW0[i] = W0[i];
    for (int i = tid; i < 64 * 64; i += 256) sW1[i] = W1[i];
    for (int i = tid; i < 33 * 64; i += 256) {
        const int c = i >> 6, j = i & 63;
        sW2T[i] = W2[j * 33 + c];
    }
    for (int i = tid; i < 64 * 41; i += 256) {
        const int u = i / 41, f = i - u * 41;
        sRW0T[u * 48 + f] = RW0[f * 64 + u];
    }
    if (tid < 64) { sb0[tid] = b0[tid]; sb1[tid] = b1[tid]; sRb0[tid] = Rb0[tid]; }
    if (tid < 33) sb2[tid] = b2[tid];
    if (tid < 192) sRW1[tid] = RW1[tid];
    if (tid < 3) sRb1[tid] = Rb1[tid];
    __syncthreads();

    const int qi = blockIdx.x * 256 + tid;
    if (qi >= n) return;
    const int i = hitq[qi];

    const float* r = rays + (size_t)i * 6;
    const float cd = t_in[i];
    const float ox = r[0], oy = r[1], oz = r[2];
    const float dx = r[3], dy = r[4], dz = r[5];
    const float px = ox + dx * cd;
    const float py = oy + dy * cd;
    const float pz = oz + dz * cd;

    // ---- forward, layer 1 accumulation ----
    float h1[64];
    #pragma unroll
    for (int j = 0; j < 64; ++j) h1[j] = 0.f;

    for (int k = 0; k < 64; ++k) {
        float z = px * sW0[k] + py * sW0[64 + k] + pz * sW0[128 + k];
        z += sb0[k];
        const float a = fmaxf(z, 0.f);
        #pragma unroll
        for (int j = 0; j < 64; ++j) h1[j] = fmaf(a, sW1[k * 64 + j], h1[j]);
    }
    #pragma unroll
    for (int j = 0; j < 64; ++j) h1[j] = fmaxf(h1[j] + sb1[j], 0.f);

    // ---- latent = out[:,1:33] ----
    float lat[32];
    #pragma unroll
    for (int c = 1; c < 33; ++c) {
        float acc = 0.f;
        #pragma unroll
        for (int j = 0; j < 64; ++j) acc = fmaf(h1[j], sW2T[c * 64 + j], acc);
        lat[c - 1] = acc + sb2[c];
    }

    // ---- backward: gz1 = (z1>0) ? W2[:,0] : 0 ----
    #pragma unroll
    for (int j = 0; j < 64; ++j) h1[j] = (h1[j] > 0.f) ? sW2T[j] : 0.f;

    float nx = 0.f, ny = 0.f, nz = 0.f;
    for (int k = 0; k < 64; ++k) {
        float z = px * sW0[k] + py * sW0[64 + k] + pz * sW0[128 + k];
        z += sb0[k];
        float g = 0.f;
        #pragma unroll
        for (int j = 0; j < 64; ++j) g = fmaf(h1[j], sW1[k * 64 + j], g);
        if (z > 0.f) {
            nx = fmaf(g, sW0[k], nx);
            ny = fmaf(g, sW0[64 + k], ny);
            nz = fmaf(g, sW0[128 + k], nz);
        }
    }

    // ---- render MLP: feat(41) = [pts, r_d, nrm, latent] ----
    float r0 = 0.f, r1 = 0.f, r2 = 0.f;
    for (int u = 0; u < 64; ++u) {
        const float* w = &sRW0T[u * 48];
        float a = px * w[0] + py * w[1] + pz * w[2];
        a = fmaf(dx, w[3], a); a = fmaf(dy, w[4], a); a = fmaf(dz, w[5], a);
        a = fmaf(nx, w[6], a); a = fmaf(ny, w[7], a); a = fmaf(nz, w[8], a);
        #pragma unroll
        for (int q = 0; q < 32; ++q) a = fmaf(lat[q], w[9 + q], a);
        a += sRb0[u];
        const float ru = fmaxf(a, 0.f);
        r0 = fmaf(ru, sRW1[u * 3 + 0], r0);
        r1 = fmaf(ru, sRW1[u * 3 + 1], r1);
        r2 = fmaf(ru, sRW1[u * 3 + 2], r2);
    }
    r0 += sRb1[0]; r1 += sRb1[1]; r2 += sRb1[2];

    out[i * 3 + 0] = 1.f / (1.f + expf(-r0));
    out[i * 3 + 1] = 1.f / (1.f + expf(-r1));
    out[i * 3 + 2] = 1.f / (1.f + expf(-r2));
}

// ---------------------------------------------------------------------------
// Fallback path (only if workspace is too small for the queues).
// ---------------------------------------------------------------------------
__global__ __launch_bounds__(256, 2)
void march_kernel(const float* __restrict__ rays,
                  const float* __restrict__ W0, const float* __restrict__ b0,
                  const float* __restrict__ W1, const float* __restrict__ b1,
                  const float* __restrict__ W2, const float* __restrict__ b2,
                  float* __restrict__ t_out, int* __restrict__ hit_out,
                  int* __restrict__ counter)
{
    float ox = 0.f, oy = 0.f, oz = 0.f, rdx = 0.f, rdy = 0.f, rdz = 0.f;
    float cd = 0.f;
    int ridx = -1, it = 0;
    bool has = false, hit = false, exhausted = false;

    const float b2_0 = b2[0];

    while (true) {
        if (!has && !exhausted) {
            int idx = atomicAdd(counter, 1);
            if (idx < NRAYS) {
                const float* r = rays + (size_t)idx * 6;
                ox = r[0]; oy = r[1]; oz = r[2];
                rdx = r[3]; rdy = r[4]; rdz = r[5];
                cd = NEARV; it = 0; hit = false; has = true; ridx = idx;
            } else {
                exhausted = true;
            }
        }
        if (__ballot(has) == 0ull) break;

        const float px = ox + rdx * cd;
        const float py = oy + rdy * cd;
        const float pz = oz + rdz * cd;

        const float d = sdf_eval(px, py, pz, W0, b0, W1, b1, W2, b2_0);

        if (has) {
            ++it;
            if (d < EPSV && cd <= FARV) hit = true;
            cd += d;
            if (hit || cd > FARV || it >= MAXIT) {
                t_out[ridx] = cd;
                hit_out[ridx] = hit ? 1 : 0;
                has = false;
            }
        }
    }
}

__global__ __launch_bounds__(256, 2)
void shade_kernel(const float* __restrict__ rays,
                  const float* __restrict__ W0, const float* __restrict__ b0,
                  const float* __restrict__ W1, const float* __restrict__ b1,
                  const float* __restrict__ W2, const float* __restrict__ b2,
                  const float* __restrict__ RW0, const float* __restrict__ Rb0,
                  const float* __restrict__ RW1, const float* __restrict__ Rb1,
                  const float* __restrict__ t_in, const int* __restrict__ hit_in,
                  float* __restrict__ out)
{
    __shared__ float sW0[3 * 64];
    __shared__ float sb0[64];
    __shared__ float sW1[64 * 64];
    __shared__ float sb1[64];
    __shared__ float sW2T[33 * 64];
    __shared__ float sb2[33];
    __shared__ float sRW0T[64 * 48];
    __shared__ float sRb0[64];
    __shared__ float sRW1[64 * 3];
    __shared__ float sRb1[3];

    const int tid = threadIdx.x;
    for (int i = tid; i < 3 * 64; i += 256) sW0[i] = W0[i];
    for (int i = tid; i < 64 * 64; i += 256) sW1[i] = W1[i];
    for (int i = tid; i < 33 * 64; i += 256) {
        const int c = i >> 6, j = i & 63;
        sW2T[i] = W2[j * 33 + c];
    }
    for (int i = tid; i < 64 * 41; i += 256) {
        const int u = i / 41, f = i - u * 41;
        sRW0T[u * 48 + f] = RW0[f * 64 + u];
    }
    if (tid < 64) { sb0[tid] = b0[tid]; sb1[tid] = b1[tid]; sRb0[tid] = Rb0[tid]; }
    if (tid < 33) sb2[tid] = b2[tid];
    if (tid < 192) sRW1[tid] = RW1[tid];
    if (tid < 3) sRb1[tid] = Rb1[tid];
    __syncthreads();

    const int i = blockIdx.x * 256 + tid;
    const bool hit = hit_in[i] != 0;

    if (__ballot(hit) == 0ull) {
        out[i * 3 + 0] = 0.f;
        out[i * 3 + 1] = 0.f;
        out[i * 3 + 2] = 0.f;
        return;
    }

    const float* r = rays + (size_t)i * 6;
    const float cd = t_in[i];
    const float ox = r[0], oy = r[1], oz = r[2];
    const float dx = r[3], dy = r[4], dz = r[5];
    const float px = ox + dx * cd;
    const float py = oy + dy * cd;
    const float pz = oz + dz * cd;

    float h1[64];
    #pragma unroll
    for (int j = 0; j < 64; ++j) h1[j] = 0.f;

    for (int k = 0; k < 64; ++k) {
        float z = px * sW0[k] + py * sW0[64 + k] + pz * sW0[128 + k];
        z += sb0[k];
        const float a = fmaxf(z, 0.f);
        #pragma unroll
        for (int j = 0; j < 64; ++j) h1[j] = fmaf(a, sW1[k * 64 + j], h1[j]);
    }
    #pragma unroll
    for (int j = 0; j < 64; ++j) h1[j] = fmaxf(h1[j] + sb1[j], 0.f);

    float lat[32];
    #pragma unroll
    for (int c = 1; c < 33; ++c) {
        float acc = 0.f;
        #pragma unroll
        for (int j = 0; j < 64; ++j) acc = fmaf(h1[j], sW2T[c * 64 + j], acc);
        lat[c - 1] = acc + sb2[c];
    }

    #pragma unroll
    for (int j = 0; j < 64; ++j) h1[j] = (h1[j] > 0.f) ? sW2T[j] : 0.f;

    float nx = 0.f, ny = 0.f, nz = 0.f;
    for (int k = 0; k < 64; ++k) {
        float z = px * sW0[k] + py * sW0[64 + k] + pz * sW0[128 + k];
        z += sb0[k];
        float g = 0.f;
        #pragma unroll
        for (int j = 0; j < 64; ++j) g = fmaf(h1[j], sW1[k * 64 + j], g);
        if (z > 0.f) {
            nx = fmaf(g, sW0[k], nx);
            ny = fmaf(g, sW0[64 + k], ny);
            nz = fmaf(g, sW0[128 + k], nz);
        }
    }
    if (!hit) { nx = 0.f; ny = 0.f; nz = 0.f; }

    float r0 = 0.f, r1 = 0.f, r2 = 0.f;
    for (int u = 0; u < 64; ++u) {
        const float* w = &sRW0T[u * 48];
        float a = px * w[0] + py * w[1] + pz * w[2];
        a = fmaf(dx, w[3], a); a = fmaf(dy, w[4], a); a = fmaf(dz, w[5], a);
        a = fmaf(nx, w[6], a); a = fmaf(ny, w[7], a); a = fmaf(nz, w[8], a);
        #pragma unroll
        for (int q = 0; q < 32; ++q) a = fmaf(lat[q], w[9 + q], a);
        a += sRb0[u];
        const float ru = fmaxf(a, 0.f);
        r0 = fmaf(ru, sRW1[u * 3 + 0], r0);
        r1 = fmaf(ru, sRW1[u * 3 + 1], r1);
        r2 = fmaf(ru, sRW1[u * 3 + 2], r2);
    }
    r0 += sRb1[0]; r1 += sRb1[1]; r2 += sRb1[2];

    const float o0 = 1.f / (1.f + expf(-r0));
    const float o1 = 1.f / (1.f + expf(-r1));
    const float o2 = 1.f / (1.f + expf(-r2));

    out[i * 3 + 0] = hit ? o0 : 0.f;
    out[i * 3 + 1] = hit ? o1 : 0.f;
    out[i * 3 + 2] = hit ? o2 : 0.f;
}

extern "C" void kernel_launch(void* const* d_in, const int* in_sizes, int n_in,
                              void* d_out, int out_size, void* d_ws, size_t ws_size,
                              hipStream_t stream) {
    const float* rays = (const float*)d_in[0];
    const float* W0   = (const float*)d_in[1];
    const float* b0   = (const float*)d_in[2];
    const float* W1   = (const float*)d_in[3];
    const float* b1   = (const float*)d_in[4];
    const float* W2   = (const float*)d_in[5];
    const float* b2   = (const float*)d_in[6];
    const float* RW0  = (const float*)d_in[7];
    const float* Rb0  = (const float*)d_in[8];
    const float* RW1  = (const float*)d_in[9];
    const float* Rb1  = (const float*)d_in[10];

    // Workspace layout (4-byte units):
    //   [0..31]                    counters: cnt[r]=survivors after round r (r<31), cnt[31]=hit count
    //   [32          .. 32+N)      t
    //   [32+N        .. 32+2N)     queue A idx
    //   [32+2N       .. 32+3N)     queue A cd
    //   [32+3N       .. 32+4N)     queue B idx
    //   [32+4N       .. 32+5N)     queue B cd
    //   [32+5N       .. 32+6N)     hit queue
    const size_t need = (size_t)(32 + 6 * NRAYS) * 4;

    if (ws_size >= need) {
        int*   cnt  = (int*)d_ws;
        float* t_ws = (float*)d_ws + 32;
        int*   qiA  = (int*)d_ws + 32 + (size_t)NRAYS;
        float* qcA  = (float*)d_ws + 32 + 2 * (size_t)NRAYS;
        int*   qiB  = (int*)d_ws + 32 + 3 * (size_t)NRAYS;
        float* qcB  = (float*)d_ws + 32 + 4 * (size_t)NRAYS;
        int*   hitq = (int*)d_ws + 32 + 5 * (size_t)NRAYS;

        hipMemsetAsync(cnt, 0, 32 * sizeof(int), stream);
        hipMemsetAsync(d_out, 0, (size_t)out_size, stream);

        // Chunk schedule: fine-grained while the death rate is high
        // (~48% of rays die in the first 16 steps, mostly at step 1),
        // coarse for the creeper tail. Sums to MAXIT = 192.
        static const int sched[NROUNDS] =
            {1, 1, 2, 4, 8, 16, 16, 16, 16, 16, 16, 16, 16, 16, 16, 16};

        const int blocks = NRAYS / MBLK;
        int it_base = 0;

        // Round 0: all rays fresh, survivors -> queue A (cnt[0]).
        march_round<<<blocks, MBLK, 0, stream>>>(
            rays, W0, b0, W1, b1, W2, b2,
            1, it_base, sched[0], nullptr, nullptr, nullptr,
            &cnt[0], qiA, qcA, t_ws, hitq, &cnt[31]);
        it_base += sched[0];

        for (int r2 = 1; r2 < NROUNDS; ++r2) {
            const int*   icnt = &cnt[r2 - 1];
            int*         ocnt = &cnt[r2];
            const int*   ii = (r2 & 1) ? qiA : qiB;
            const float* ic = (r2 & 1) ? qcA : qcB;
            int*         oi = (r2 & 1) ? qiB : qiA;
            float*       oc = (r2 & 1) ? qcB : qcA;
            march_round<<<blocks, MBLK, 0, stream>>>(
                rays, W0, b0, W1, b1, W2, b2,
                0, it_base, sched[r2], icnt, ii, ic,
                ocnt, oi, oc, t_ws, hitq, &cnt[31]);
            it_base += sched[r2];
        }

        shade_hit<<<NRAYS / 256, 256, 0, stream>>>(
            rays, W0, b0, W1, b1, W2, b2, RW0, Rb0, RW1, Rb1,
            t_ws, hitq, &cnt[31], (float*)d_out);
    } else {
        // Fallback: previous passing path.
        float* t_ws  = (float*)d_ws;
        int*   hit_ws = (int*)d_ws + NRAYS;
        int*   ctr    = (int*)d_ws + 2 * NRAYS;

        hipMemsetAsync(ctr, 0, sizeof(int), stream);
        march_kernel<<<1024, 256, 0, stream>>>(rays, W0, b0, W1, b1, W2, b2,
                                               t_ws, hit_ws, ctr);
        shade_kernel<<<NRAYS / 256, 256, 0, stream>>>(rays, W0, b0, W1, b1, W2, b2,
                                                      RW0, Rb0, RW1, Rb1,
                                                      t_ws, hit_ws, (float*)d_out);
    }
}

// Round 11
// 3669.273 us; speedup vs baseline: 1.1322x; 1.0106x over previous
//
#include <hip/hip_runtime.h>
#include <math.h>

#define NRAYS 262144
#define MAXIT 192
#define NEARV 0.2f
#define FARV  2.0f
#define EPSV  0.001f
#define MBLK 512      // march block size (8 waves)
#define NROUNDS 16    // schedule: 1,1,2,4,8 then 11x16 = 192 steps

// ---------------------------------------------------------------------------
// Single-ray SDF MLP eval (fallback path only) — canonical fma order,
// scalar weight loads.
// ---------------------------------------------------------------------------
__device__ __forceinline__ float sdf_eval(
    float px, float py, float pz,
    const float* __restrict__ W0, const float* __restrict__ b0,
    const float* __restrict__ W1, const float* __restrict__ b1,
    const float* __restrict__ W2, float b2_0)
{
    float h1[64];
    #pragma unroll
    for (int j = 0; j < 64; ++j) h1[j] = 0.f;

    for (int k = 0; k < 64; ++k) {
        float z = px * W0[k] + py * W0[64 + k] + pz * W0[128 + k];
        z += b0[k];
        const float a = fmaxf(z, 0.f);
        #pragma unroll
        for (int j = 0; j < 64; ++j) h1[j] = fmaf(a, W1[k * 64 + j], h1[j]);
    }

    float d = 0.f;
    #pragma unroll
    for (int j = 0; j < 64; ++j)
        d = fmaf(fmaxf(h1[j] + b1[j], 0.f), W2[j * 33], d);
    return d + b2_0;
}

// ---------------------------------------------------------------------------
// R8 march kernel (best measured: 66.7% VALUBusy, single-pass codegen)
// with a RUNTIME chunk length. Inner loop is bit-identical to R8.
//   - (512,2): 256-reg unified budget -> h1[64] stays single-pass (R8).
//   - raw s_barrier per 8 k's: phase-locks block waves into one K$ window
//     (R6: busy 58.6->73.5%); no data crosses it, no waitcnt drain.
//   - kchunk argument: early rounds use short chunks (1,1,2,4,8) so rays
//     that die at step 1 stop burning dead steps; creeper rounds use 16.
// fma order identical to sdf_eval -> bit-identical t/hit.
// ---------------------------------------------------------------------------
__global__ __launch_bounds__(MBLK, 2)
void march_round(const float* __restrict__ rays,
                 const float* __restrict__ W0, const float* __restrict__ b0,
                 const float* __restrict__ W1, const float* __restrict__ b1,
                 const float* __restrict__ W2, const float* __restrict__ b2,
                 int round0, int it_base, int kchunk,
                 const int* __restrict__ in_cnt,
                 const int* __restrict__ in_idx, const float* __restrict__ in_cd,
                 int* __restrict__ out_cnt,
                 int* __restrict__ out_idx, float* __restrict__ out_cd,
                 float* __restrict__ t_out,
                 int* __restrict__ hitq, int* __restrict__ hit_cnt)
{
    const int i    = blockIdx.x * MBLK + threadIdx.x;
    const int lane = threadIdx.x & 63;
    const int n    = round0 ? NRAYS : *in_cnt;

    // Block-uniform early exit BEFORE any barrier (empty tail blocks).
    if (blockIdx.x * MBLK >= n) return;

    bool alive = (i < n);
    bool hit   = false;
    int  ridx  = 0;
    float cd   = NEARV;
    int  it    = it_base;

    if (alive) {
        if (round0) {
            ridx = i;
        } else {
            ridx = in_idx[i];
            cd   = in_cd[i];
        }
    }

    const float* r = rays + (size_t)ridx * 6;   // dead lanes read ray 0 (in-bounds)
    const float ox = r[0], oy = r[1], oz = r[2];
    const float rdx = r[3], rdy = r[4], rdz = r[5];
    const float b2_0 = b2[0];

    // Fixed trip count: every wave executes every barrier.
    for (int s = 0; s < kchunk; ++s) {
        const float px = ox + rdx * cd;
        const float py = oy + rdy * cd;
        const float pz = oz + rdz * cd;

        float h1[64];
        #pragma unroll
        for (int j = 0; j < 64; ++j) h1[j] = 0.f;

        for (int kt = 0; kt < 8; ++kt) {
            #pragma unroll
            for (int kk = 0; kk < 8; ++kk) {
                const int k = kt * 8 + kk;
                float z = px * W0[k] + py * W0[64 + k] + pz * W0[128 + k];
                z += b0[k];
                const float a = fmaxf(z, 0.f);
                #pragma unroll
                for (int j = 0; j < 64; ++j)
                    h1[j] = fmaf(a, W1[k * 64 + j], h1[j]);
            }
            // Phase clamp only (raw s_barrier, not __syncthreads).
            __builtin_amdgcn_s_barrier();
        }

        float d = 0.f;
        #pragma unroll
        for (int j = 0; j < 64; ++j)
            d = fmaf(fmaxf(h1[j] + b1[j], 0.f), W2[j * 33], d);
        d += b2_0;

        if (alive) {
            ++it;
            if (d < EPSV && cd <= FARV) hit = true;
            cd += d;
            if (hit || cd > FARV || it >= MAXIT) {
                t_out[ridx] = cd;
                if (hit) {
                    const int p = atomicAdd(hit_cnt, 1);
                    hitq[p] = ridx;
                }
                alive = false;
            }
        }
    }

    // Wave-aggregated compaction of survivors into the out-queue.
    const unsigned long long m = __ballot(alive);
    if (m != 0ull) {
        const int leader = __builtin_ctzll(m);
        int base = 0;
        if (lane == leader) base = atomicAdd(out_cnt, __builtin_popcountll(m));
        base = __shfl(base, leader);
        if (alive) {
            const int off = __builtin_popcountll(m & ((1ull << lane) - 1ull));
            out_idx[base + off] = ridx;
            out_cd[base + off]  = cd;
        }
    }
}

// ---------------------------------------------------------------------------
// Shade only the hit rays (dense hit queue). Output memset to zero.
// __launch_bounds__(256, 1): 512-reg unified budget. Under (256,2) the
// compiler allocated 128 VGPRs and spilled ~1.4KB/thread of h1/lat/temps
// to scratch -> 372 MB HBM writes + 190 MB fetch per dispatch (measured
// R10: WRITE_SIZE=372151 KB, VALUBusy 3.9% — shade was a scratch-BW
// kernel). Same fix as R8's march: give the unified file room.
// Arithmetic bit-identical to the passing shade kernel.
// ---------------------------------------------------------------------------
__global__ __launch_bounds__(256, 1)
void shade_hit(const float* __restrict__ rays,
               const float* __restrict__ W0, const float* __restrict__ b0,
               const float* __restrict__ W1, const float* __restrict__ b1,
               const float* __restrict__ W2, const float* __restrict__ b2,
               const float* __restrict__ RW0, const float* __restrict__ Rb0,
               const float* __restrict__ RW1, const float* __restrict__ Rb1,
               const float* __restrict__ t_in,
               const int* __restrict__ hitq, const int* __restrict__ hit_cnt,
               float* __restrict__ out)
{
    const int n = *hit_cnt;
    if (blockIdx.x * 256 >= n) return;   // whole block empty -> skip staging

    __shared__ float sW0[3 * 64];
    __shared__ float sb0[64];
    __shared__ float sW1[64 * 64];
    __shared__ float sb1[64];
    __shared__ float sW2T[33 * 64];   // [c][j] = W2[j][c]
    __shared__ float sb2[33];
    __shared__ float sRW0T[64 * 48];  // [u][f] = RW0[f][u], padded 41->48
    __shared__ float sRb0[64];
    __shared__ float sRW1[64 * 3];
    __shared__ float sRb1[3];

    const int tid = threadIdx.x;
    for (int i = tid; i < 3 * 64; i += 256) sW0[i] = W0[i];
    for (int i = tid; i < 64 * 64; i += 256) sW1[i] = W1[i];
    for (int i = tid; i < 33 * 64; i += 256) {
        const int c = i >> 6, j = i & 63;
        sW2T[i] = W2[j * 33 + c];
    }
    for (int i = tid; i < 64 * 41; i += 256) {
        const int u = i / 41, f = i - u * 41;
        sRW0T[u * 48 + f] = RW0[f * 64 + u];
    }
    if (tid < 64) { sb0[tid] = b0[tid]; sb1[tid] = b1[tid]; sRb0[tid] = Rb0[tid]; }
    if (tid < 33) sb2[tid] = b2[tid];
    if (tid < 192) sRW1[tid] = RW1[tid];
    if (tid < 3) sRb1[tid] = Rb1[tid];
    __syncthreads();

    const int qi = blockIdx.x * 256 + tid;
    if (qi >= n) return;
    const int i = hitq[qi];

    const float* r = rays + (size_t)i * 6;
    const float cd = t_in[i];
    const float ox = r[0], oy = r[1], oz = r[2];
    const float dx = r[3], dy = r[4], dz = r[5];
    const float px = ox + dx * cd;
    const float py = oy + dy * cd;
    const float pz = oz + dz * cd;

    // ---- forward, layer 1 accumulation ----
    float h1[64];
    #pragma unroll
    for (int j = 0; j < 64; ++j) h1[j] = 0.f;

    for (int k = 0; k < 64; ++k) {
        float z = px * sW0[k] + py * sW0[64 + k] + pz * sW0[128 + k];
        z += sb0[k];
        const float a = fmaxf(z, 0.f);
        #pragma unroll
        for (int j = 0; j < 64; ++j) h1[j] = fmaf(a, sW1[k * 64 + j], h1[j]);
    }
    #pragma unroll
    for (int j = 0; j < 64; ++j) h1[j] = fmaxf(h1[j] + sb1[j], 0.f);

    // ---- latent = out[:,1:33] ----
    float lat[32];
    #pragma unroll
    for (int c = 1; c < 33; ++c) {
        float acc = 0.f;
        #pragma unroll
        for (int j = 0; j < 64; ++j) acc = fmaf(h1[j], sW2T[c * 64 + j], acc);
        lat[c - 1] = acc + sb2[c];
    }

    // ---- backward: gz1 = (z1>0) ? W2[:,0] : 0 ----
    #pragma unroll
    for (int j = 0; j < 64; ++j) h1[j] = (h1[j] > 0.f) ? sW2T[j] : 0.f;

    float nx = 0.f, ny = 0.f, nz = 0.f;
    for (int k = 0; k < 64; ++k) {
        float z = px * sW0[k] + py * sW0[64 + k] + pz * sW0[128 + k];
        z += sb0[k];
        float g = 0.f;
        #pragma unroll
        for (int j = 0; j < 64; ++j) g = fmaf(h1[j], sW1[k * 64 + j], g);
        if (z > 0.f) {
            nx = fmaf(g, sW0[k], nx);
            ny = fmaf(g, sW0[64 + k], ny);
            nz = fmaf(g, sW0[128 + k], nz);
        }
    }

    // ---- render MLP: feat(41) = [pts, r_d, nrm, latent] ----
    float r0 = 0.f, r1 = 0.f, r2 = 0.f;
    for (int u = 0; u < 64; ++u) {
        const float* w = &sRW0T[u * 48];
        float a = px * w[0] + py * w[1] + pz * w[2];
        a = fmaf(dx, w[3], a); a = fmaf(dy, w[4], a); a = fmaf(dz, w[5], a);
        a = fmaf(nx, w[6], a); a = fmaf(ny, w[7], a); a = fmaf(nz, w[8], a);
        #pragma unroll
        for (int q = 0; q < 32; ++q) a = fmaf(lat[q], w[9 + q], a);
        a += sRb0[u];
        const float ru = fmaxf(a, 0.f);
        r0 = fmaf(ru, sRW1[u * 3 + 0], r0);
        r1 = fmaf(ru, sRW1[u * 3 + 1], r1);
        r2 = fmaf(ru, sRW1[u * 3 + 2], r2);
    }
    r0 += sRb1[0]; r1 += sRb1[1]; r2 += sRb1[2];

    out[i * 3 + 0] = 1.f / (1.f + expf(-r0));
    out[i * 3 + 1] = 1.f / (1.f + expf(-r1));
    out[i * 3 + 2] = 1.f / (1.f + expf(-r2));
}

// ---------------------------------------------------------------------------
// Fallback path (only if workspace is too small for the queues).
// ---------------------------------------------------------------------------
__global__ __launch_bounds__(256, 2)
void march_kernel(const float* __restrict__ rays,
                  const float* __restrict__ W0, const float* __restrict__ b0,
                  const float* __restrict__ W1, const float* __restrict__ b1,
                  const float* __restrict__ W2, const float* __restrict__ b2,
                  float* __restrict__ t_out, int* __restrict__ hit_out,
                  int* __restrict__ counter)
{
    float ox = 0.f, oy = 0.f, oz = 0.f, rdx = 0.f, rdy = 0.f, rdz = 0.f;
    float cd = 0.f;
    int ridx = -1, it = 0;
    bool has = false, hit = false, exhausted = false;

    const float b2_0 = b2[0];

    while (true) {
        if (!has && !exhausted) {
            int idx = atomicAdd(counter, 1);
            if (idx < NRAYS) {
                const float* r = rays + (size_t)idx * 6;
                ox = r[0]; oy = r[1]; oz = r[2];
                rdx = r[3]; rdy = r[4]; rdz = r[5];
                cd = NEARV; it = 0; hit = false; has = true; ridx = idx;
            } else {
                exhausted = true;
            }
        }
        if (__ballot(has) == 0ull) break;

        const float px = ox + rdx * cd;
        const float py = oy + rdy * cd;
        const float pz = oz + rdz * cd;

        const float d = sdf_eval(px, py, pz, W0, b0, W1, b1, W2, b2_0);

        if (has) {
            ++it;
            if (d < EPSV && cd <= FARV) hit = true;
            cd += d;
            if (hit || cd > FARV || it >= MAXIT) {
                t_out[ridx] = cd;
                hit_out[ridx] = hit ? 1 : 0;
                has = false;
            }
        }
    }
}

__global__ __launch_bounds__(256, 2)
void shade_kernel(const float* __restrict__ rays,
                  const float* __restrict__ W0, const float* __restrict__ b0,
                  const float* __restrict__ W1, const float* __restrict__ b1,
                  const float* __restrict__ W2, const float* __restrict__ b2,
                  const float* __restrict__ RW0, const float* __restrict__ Rb0,
                  const float* __restrict__ RW1, const float* __restrict__ Rb1,
                  const float* __restrict__ t_in, const int* __restrict__ hit_in,
                  float* __restrict__ out)
{
    __shared__ float sW0[3 * 64];
    __shared__ float sb0[64];
    __shared__ float sW1[64 * 64];
    __shared__ float sb1[64];
    __shared__ float sW2T[33 * 64];
    __shared__ float sb2[33];
    __shared__ float sRW0T[64 * 48];
    __shared__ float sRb0[64];
    __shared__ float sRW1[64 * 3];
    __shared__ float sRb1[3];

    const int tid = threadIdx.x;
    for (int i = tid; i < 3 * 64; i += 256) sW0[i] = W0[i];
    for (int i = tid; i < 64 * 64; i += 256) sW1[i] = W1[i];
    for (int i = tid; i < 33 * 64; i += 256) {
        const int c = i >> 6, j = i & 63;
        sW2T[i] = W2[j * 33 + c];
    }
    for (int i = tid; i < 64 * 41; i += 256) {
        const int u = i / 41, f = i - u * 41;
        sRW0T[u * 48 + f] = RW0[f * 64 + u];
    }
    if (tid < 64) { sb0[tid] = b0[tid]; sb1[tid] = b1[tid]; sRb0[tid] = Rb0[tid]; }
    if (tid < 33) sb2[tid] = b2[tid];
    if (tid < 192) sRW1[tid] = RW1[tid];
    if (tid < 3) sRb1[tid] = Rb1[tid];
    __syncthreads();

    const int i = blockIdx.x * 256 + tid;
    const bool hit = hit_in[i] != 0;

    if (__ballot(hit) == 0ull) {
        out[i * 3 + 0] = 0.f;
        out[i * 3 + 1] = 0.f;
        out[i * 3 + 2] = 0.f;
        return;
    }

    const float* r = rays + (size_t)i * 6;
    const float cd = t_in[i];
    const float ox = r[0], oy = r[1], oz = r[2];
    const float dx = r[3], dy = r[4], dz = r[5];
    const float px = ox + dx * cd;
    const float py = oy + dy * cd;
    const float pz = oz + dz * cd;

    float h1[64];
    #pragma unroll
    for (int j = 0; j < 64; ++j) h1[j] = 0.f;

    for (int k = 0; k < 64; ++k) {
        float z = px * sW0[k] + py * sW0[64 + k] + pz * sW0[128 + k];
        z += sb0[k];
        const float a = fmaxf(z, 0.f);
        #pragma unroll
        for (int j = 0; j < 64; ++j) h1[j] = fmaf(a, sW1[k * 64 + j], h1[j]);
    }
    #pragma unroll
    for (int j = 0; j < 64; ++j) h1[j] = fmaxf(h1[j] + sb1[j], 0.f);

    float lat[32];
    #pragma unroll
    for (int c = 1; c < 33; ++c) {
        float acc = 0.f;
        #pragma unroll
        for (int j = 0; j < 64; ++j) acc = fmaf(h1[j], sW2T[c * 64 + j], acc);
        lat[c - 1] = acc + sb2[c];
    }

    #pragma unroll
    for (int j = 0; j < 64; ++j) h1[j] = (h1[j] > 0.f) ? sW2T[j] : 0.f;

    float nx = 0.f, ny = 0.f, nz = 0.f;
    for (int k = 0; k < 64; ++k) {
        float z = px * sW0[k] + py * sW0[64 + k] + pz * sW0[128 + k];
        z += sb0[k];
        float g = 0.f;
        #pragma unroll
        for (int j = 0; j < 64; ++j) g = fmaf(h1[j], sW1[k * 64 + j], g);
        if (z > 0.f) {
            nx = fmaf(g, sW0[k], nx);
            ny = fmaf(g, sW0[64 + k], ny);
            nz = fmaf(g, sW0[128 + k], nz);
        }
    }
    if (!hit) { nx = 0.f; ny = 0.f; nz = 0.f; }

    float r0 = 0.f, r1 = 0.f, r2 = 0.f;
    for (int u = 0; u < 64; ++u) {
        const float* w = &sRW0T[u * 48];
        float a = px * w[0] + py * w[1] + pz * w[2];
        a = fmaf(dx, w[3], a); a = fmaf(dy, w[4], a); a = fmaf(dz, w[5], a);
        a = fmaf(nx, w[6], a); a = fmaf(ny, w[7], a); a = fmaf(nz, w[8], a);
        #pragma unroll
        for (int q = 0; q < 32; ++q) a = fmaf(lat[q], w[9 + q], a);
        a += sRb0[u];
        const float ru = fmaxf(a, 0.f);
        r0 = fmaf(ru, sRW1[u * 3 + 0], r0);
        r1 = fmaf(ru, sRW1[u * 3 + 1], r1);
        r2 = fmaf(ru, sRW1[u * 3 + 2], r2);
    }
    r0 += sRb1[0]; r1 += sRb1[1]; r2 += sRb1[2];

    const float o0 = 1.f / (1.f + expf(-r0));
    const float o1 = 1.f / (1.f + expf(-r1));
    const float o2 = 1.f / (1.f + expf(-r2));

    out[i * 3 + 0] = hit ? o0 : 0.f;
    out[i * 3 + 1] = hit ? o1 : 0.f;
    out[i * 3 + 2] = hit ? o2 : 0.f;
}

extern "C" void kernel_launch(void* const* d_in, const int* in_sizes, int n_in,
                              void* d_out, int out_size, void* d_ws, size_t ws_size,
                              hipStream_t stream) {
    const float* rays = (const float*)d_in[0];
    const float* W0   = (const float*)d_in[1];
    const float* b0   = (const float*)d_in[2];
    const float* W1   = (const float*)d_in[3];
    const float* b1   = (const float*)d_in[4];
    const float* W2   = (const float*)d_in[5];
    const float* b2   = (const float*)d_in[6];
    const float* RW0  = (const float*)d_in[7];
    const float* Rb0  = (const float*)d_in[8];
    const float* RW1  = (const float*)d_in[9];
    const float* Rb1  = (const float*)d_in[10];

    // Workspace layout (4-byte units):
    //   [0..31]                    counters: cnt[r]=survivors after round r (r<31), cnt[31]=hit count
    //   [32          .. 32+N)      t
    //   [32+N        .. 32+2N)     queue A idx
    //   [32+2N       .. 32+3N)     queue A cd
    //   [32+3N       .. 32+4N)     queue B idx
    //   [32+4N       .. 32+5N)     queue B cd
    //   [32+5N       .. 32+6N)     hit queue
    const size_t need = (size_t)(32 + 6 * NRAYS) * 4;

    if (ws_size >= need) {
        int*   cnt  = (int*)d_ws;
        float* t_ws = (float*)d_ws + 32;
        int*   qiA  = (int*)d_ws + 32 + (size_t)NRAYS;
        float* qcA  = (float*)d_ws + 32 + 2 * (size_t)NRAYS;
        int*   qiB  = (int*)d_ws + 32 + 3 * (size_t)NRAYS;
        float* qcB  = (float*)d_ws + 32 + 4 * (size_t)NRAYS;
        int*   hitq = (int*)d_ws + 32 + 5 * (size_t)NRAYS;

        hipMemsetAsync(cnt, 0, 32 * sizeof(int), stream);
        hipMemsetAsync(d_out, 0, (size_t)out_size, stream);

        // Chunk schedule: fine-grained while the death rate is high,
        // coarse for the creeper tail. Sums to MAXIT = 192.
        static const int sched[NROUNDS] =
            {1, 1, 2, 4, 8, 16, 16, 16, 16, 16, 16, 16, 16, 16, 16, 16};

        const int blocks = NRAYS / MBLK;
        int it_base = 0;

        // Round 0: all rays fresh, survivors -> queue A (cnt[0]).
        march_round<<<blocks, MBLK, 0, stream>>>(
            rays, W0, b0, W1, b1, W2, b2,
            1, it_base, sched[0], nullptr, nullptr, nullptr,
            &cnt[0], qiA, qcA, t_ws, hitq, &cnt[31]);
        it_base += sched[0];

        for (int r2 = 1; r2 < NROUNDS; ++r2) {
            const int*   icnt = &cnt[r2 - 1];
            int*         ocnt = &cnt[r2];
            const int*   ii = (r2 & 1) ? qiA : qiB;
            const float* ic = (r2 & 1) ? qcA : qcB;
            int*         oi = (r2 & 1) ? qiB : qiA;
            float*       oc = (r2 & 1) ? qcB : qcA;
            march_round<<<blocks, MBLK, 0, stream>>>(
                rays, W0, b0, W1, b1, W2, b2,
                0, it_base, sched[r2], icnt, ii, ic,
                ocnt, oi, oc, t_ws, hitq, &cnt[31]);
            it_base += sched[r2];
        }

        shade_hit<<<NRAYS / 256, 256, 0, stream>>>(
            rays, W0, b0, W1, b1, W2, b2, RW0, Rb0, RW1, Rb1,
            t_ws, hitq, &cnt[31], (float*)d_out);
    } else {
        // Fallback: previous passing path.
        float* t_ws  = (float*)d_ws;
        int*   hit_ws = (int*)d_ws + NRAYS;
        int*   ctr    = (int*)d_ws + 2 * NRAYS;

        hipMemsetAsync(ctr, 0, sizeof(int), stream);
        march_kernel<<<1024, 256, 0, stream>>>(rays, W0, b0, W1, b1, W2, b2,
                                               t_ws, hit_ws, ctr);
        shade_kernel<<<NRAYS / 256, 256, 0, stream>>>(rays, W0, b0, W1, b1, W2, b2,
                                                      RW0, Rb0, RW1, Rb1,
                                                      t_ws, hit_ws, (float*)d_out);
    }
}

// Round 12
// 3386.327 us; speedup vs baseline: 1.2267x; 1.0836x over previous
//
#include <hip/hip_runtime.h>
#include <math.h>

#define NRAYS 262144
#define MAXIT 192
#define NEARV 0.2f
#define FARV  2.0f
#define EPSV  0.001f
#define MBLK 512      // march block size (8 waves)
#define NROUNDS 16    // schedule: 1,1,2,4,8 then 11x16 = 192 steps

// ---------------------------------------------------------------------------
// Single-ray SDF MLP eval (fallback path only) — canonical fma order,
// scalar weight loads.
// ---------------------------------------------------------------------------
__device__ __forceinline__ float sdf_eval(
    float px, float py, float pz,
    const float* __restrict__ W0, const float* __restrict__ b0,
    const float* __restrict__ W1, const float* __restrict__ b1,
    const float* __restrict__ W2, float b2_0)
{
    float h1[64];
    #pragma unroll
    for (int j = 0; j < 64; ++j) h1[j] = 0.f;

    for (int k = 0; k < 64; ++k) {
        float z = px * W0[k] + py * W0[64 + k] + pz * W0[128 + k];
        z += b0[k];
        const float a = fmaxf(z, 0.f);
        #pragma unroll
        for (int j = 0; j < 64; ++j) h1[j] = fmaf(a, W1[k * 64 + j], h1[j]);
    }

    float d = 0.f;
    #pragma unroll
    for (int j = 0; j < 64; ++j)
        d = fmaf(fmaxf(h1[j] + b1[j], 0.f), W2[j * 33], d);
    return d + b2_0;
}

// ---------------------------------------------------------------------------
// R8 march kernel (best measured: 66.7% VALUBusy, single-pass codegen)
// with a RUNTIME chunk length. Inner loop is bit-identical to R8.
//   - (512,2): 256-reg unified budget -> h1[64] stays single-pass (R8).
//   - raw s_barrier per 8 k's: phase-locks block waves into one K$ window
//     (R6: busy 58.6->73.5%); no data crosses it, no waitcnt drain.
//   - kchunk argument: early rounds use short chunks (1,1,2,4,8) so rays
//     that die at step 1 stop burning dead steps; creeper rounds use 16.
// fma order identical to sdf_eval -> bit-identical t/hit.
// ---------------------------------------------------------------------------
__global__ __launch_bounds__(MBLK, 2)
void march_round(const float* __restrict__ rays,
                 const float* __restrict__ W0, const float* __restrict__ b0,
                 const float* __restrict__ W1, const float* __restrict__ b1,
                 const float* __restrict__ W2, const float* __restrict__ b2,
                 int round0, int it_base, int kchunk,
                 const int* __restrict__ in_cnt,
                 const int* __restrict__ in_idx, const float* __restrict__ in_cd,
                 int* __restrict__ out_cnt,
                 int* __restrict__ out_idx, float* __restrict__ out_cd,
                 float* __restrict__ t_out,
                 int* __restrict__ hitq, int* __restrict__ hit_cnt)
{
    const int i    = blockIdx.x * MBLK + threadIdx.x;
    const int lane = threadIdx.x & 63;
    const int n    = round0 ? NRAYS : *in_cnt;

    // Block-uniform early exit BEFORE any barrier (empty tail blocks).
    if (blockIdx.x * MBLK >= n) return;

    bool alive = (i < n);
    bool hit   = false;
    int  ridx  = 0;
    float cd   = NEARV;
    int  it    = it_base;

    if (alive) {
        if (round0) {
            ridx = i;
        } else {
            ridx = in_idx[i];
            cd   = in_cd[i];
        }
    }

    const float* r = rays + (size_t)ridx * 6;   // dead lanes read ray 0 (in-bounds)
    const float ox = r[0], oy = r[1], oz = r[2];
    const float rdx = r[3], rdy = r[4], rdz = r[5];
    const float b2_0 = b2[0];

    // Fixed trip count: every wave executes every barrier.
    for (int s = 0; s < kchunk; ++s) {
        const float px = ox + rdx * cd;
        const float py = oy + rdy * cd;
        const float pz = oz + rdz * cd;

        float h1[64];
        #pragma unroll
        for (int j = 0; j < 64; ++j) h1[j] = 0.f;

        for (int kt = 0; kt < 8; ++kt) {
            #pragma unroll
            for (int kk = 0; kk < 8; ++kk) {
                const int k = kt * 8 + kk;
                float z = px * W0[k] + py * W0[64 + k] + pz * W0[128 + k];
                z += b0[k];
                const float a = fmaxf(z, 0.f);
                #pragma unroll
                for (int j = 0; j < 64; ++j)
                    h1[j] = fmaf(a, W1[k * 64 + j], h1[j]);
            }
            // Phase clamp only (raw s_barrier, not __syncthreads).
            __builtin_amdgcn_s_barrier();
        }

        float d = 0.f;
        #pragma unroll
        for (int j = 0; j < 64; ++j)
            d = fmaf(fmaxf(h1[j] + b1[j], 0.f), W2[j * 33], d);
        d += b2_0;

        if (alive) {
            ++it;
            if (d < EPSV && cd <= FARV) hit = true;
            cd += d;
            if (hit || cd > FARV || it >= MAXIT) {
                t_out[ridx] = cd;
                if (hit) {
                    const int p = atomicAdd(hit_cnt, 1);
                    hitq[p] = ridx;
                }
                alive = false;
            }
        }
    }

    // Wave-aggregated compaction of survivors into the out-queue.
    const unsigned long long m = __ballot(alive);
    if (m != 0ull) {
        const int leader = __builtin_ctzll(m);
        int base = 0;
        if (lane == leader) base = atomicAdd(out_cnt, __builtin_popcountll(m));
        base = __shfl(base, leader);
        if (alive) {
            const int off = __builtin_popcountll(m & ((1ull << lane) - 1ull));
            out_idx[base + off] = ridx;
            out_cd[base + off]  = cd;
        }
    }
}

// ---------------------------------------------------------------------------
// Shade only the hit rays (dense hit queue). Output memset to zero.
// REBUILT on the march recipe: ALL weights via the wave-uniform SCALAR path
// (zero LDS), 512-thread blocks, (512,2) budget, s_barrier phase-lock on
// the two W1-streaming loops. Why: R10/R11 showed the LDS-weight version
// spilled ~1.2KB/thread even at 256 VGPRs (WRITE_SIZE 324-372 MB, VALUBusy
// 4%) — every ds_read occupies a VGPR and the scheduler's load hoisting
// across the unrolled latent block blew out liveness. March proves the
// scalar path holds h1[64] spill-free at 48 VGPRs. Weight values and fma
// order are EXACTLY the passing kernel's (sW2T[c*64+j] == W2[j*33+c],
// sRW0T[u*48+f] == RW0[f*64+u]) -> bit-identical output.
// Dead lanes clamp qi -> hitq[0], compute garbage, skip the store (must
// exist for uniform barrier participation).
// ---------------------------------------------------------------------------
__global__ __launch_bounds__(MBLK, 2)
void shade_hit(const float* __restrict__ rays,
               const float* __restrict__ W0, const float* __restrict__ b0,
               const float* __restrict__ W1, const float* __restrict__ b1,
               const float* __restrict__ W2, const float* __restrict__ b2,
               const float* __restrict__ RW0, const float* __restrict__ Rb0,
               const float* __restrict__ RW1, const float* __restrict__ Rb1,
               const float* __restrict__ t_in,
               const int* __restrict__ hitq, const int* __restrict__ hit_cnt,
               float* __restrict__ out)
{
    const int n = *hit_cnt;
    if (blockIdx.x * MBLK >= n) return;   // block-uniform exit, pre-barrier

    const int qi    = blockIdx.x * MBLK + threadIdx.x;
    const bool valid = (qi < n);
    const int i     = hitq[valid ? qi : 0];   // dead lanes clamp to hitq[0]

    const float* r = rays + (size_t)i * 6;
    const float cd = t_in[i];
    const float ox = r[0], oy = r[1], oz = r[2];
    const float dx = r[3], dy = r[4], dz = r[5];
    const float px = ox + dx * cd;
    const float py = oy + dy * cd;
    const float pz = oz + dz * cd;

    // ---- forward, layer 1 accumulation (scalar weights, phase-locked) ----
    float h1[64];
    #pragma unroll
    for (int j = 0; j < 64; ++j) h1[j] = 0.f;

    for (int kt = 0; kt < 8; ++kt) {
        #pragma unroll
        for (int kk = 0; kk < 8; ++kk) {
            const int k = kt * 8 + kk;
            float z = px * W0[k] + py * W0[64 + k] + pz * W0[128 + k];
            z += b0[k];
            const float a = fmaxf(z, 0.f);
            #pragma unroll
            for (int j = 0; j < 64; ++j) h1[j] = fmaf(a, W1[k * 64 + j], h1[j]);
        }
        __builtin_amdgcn_s_barrier();   // phase clamp only
    }
    #pragma unroll
    for (int j = 0; j < 64; ++j) h1[j] = fmaxf(h1[j] + b1[j], 0.f);

    // ---- latent = out[:,1:33]  (W2[j*33+c] == old sW2T[c*64+j]) ----
    float lat[32];
    #pragma unroll
    for (int c = 1; c < 33; ++c) {
        float acc = 0.f;
        #pragma unroll
        for (int j = 0; j < 64; ++j) acc = fmaf(h1[j], W2[j * 33 + c], acc);
        lat[c - 1] = acc + b2[c];
    }

    // ---- backward: gz1 = (z1>0) ? W2[:,0] : 0 ----
    #pragma unroll
    for (int j = 0; j < 64; ++j) h1[j] = (h1[j] > 0.f) ? W2[j * 33] : 0.f;

    float nx = 0.f, ny = 0.f, nz = 0.f;
    for (int kt = 0; kt < 8; ++kt) {
        #pragma unroll
        for (int kk = 0; kk < 8; ++kk) {
            const int k = kt * 8 + kk;
            float z = px * W0[k] + py * W0[64 + k] + pz * W0[128 + k];
            z += b0[k];
            float g = 0.f;
            #pragma unroll
            for (int j = 0; j < 64; ++j) g = fmaf(h1[j], W1[k * 64 + j], g);
            if (z > 0.f) {
                nx = fmaf(g, W0[k], nx);
                ny = fmaf(g, W0[64 + k], ny);
                nz = fmaf(g, W0[128 + k], nz);
            }
        }
        __builtin_amdgcn_s_barrier();   // phase clamp only
    }

    // ---- render MLP  (RW0[f*64+u] == old sRW0T[u*48+f]) ----
    float r0 = 0.f, r1 = 0.f, r2 = 0.f;
    for (int u = 0; u < 64; ++u) {
        float a = px * RW0[u] + py * RW0[64 + u] + pz * RW0[128 + u];
        a = fmaf(dx, RW0[3 * 64 + u], a);
        a = fmaf(dy, RW0[4 * 64 + u], a);
        a = fmaf(dz, RW0[5 * 64 + u], a);
        a = fmaf(nx, RW0[6 * 64 + u], a);
        a = fmaf(ny, RW0[7 * 64 + u], a);
        a = fmaf(nz, RW0[8 * 64 + u], a);
        #pragma unroll
        for (int q = 0; q < 32; ++q) a = fmaf(lat[q], RW0[(9 + q) * 64 + u], a);
        a += Rb0[u];
        const float ru = fmaxf(a, 0.f);
        r0 = fmaf(ru, RW1[u * 3 + 0], r0);
        r1 = fmaf(ru, RW1[u * 3 + 1], r1);
        r2 = fmaf(ru, RW1[u * 3 + 2], r2);
    }
    r0 += Rb1[0]; r1 += Rb1[1]; r2 += Rb1[2];

    if (valid) {
        out[i * 3 + 0] = 1.f / (1.f + expf(-r0));
        out[i * 3 + 1] = 1.f / (1.f + expf(-r1));
        out[i * 3 + 2] = 1.f / (1.f + expf(-r2));
    }
}

// ---------------------------------------------------------------------------
// Fallback path (only if workspace is too small for the queues).
// ---------------------------------------------------------------------------
__global__ __launch_bounds__(256, 2)
void march_kernel(const float* __restrict__ rays,
                  const float* __restrict__ W0, const float* __restrict__ b0,
                  const float* __restrict__ W1, const float* __restrict__ b1,
                  const float* __restrict__ W2, const float* __restrict__ b2,
                  float* __restrict__ t_out, int* __restrict__ hit_out,
                  int* __restrict__ counter)
{
    float ox = 0.f, oy = 0.f, oz = 0.f, rdx = 0.f, rdy = 0.f, rdz = 0.f;
    float cd = 0.f;
    int ridx = -1, it = 0;
    bool has = false, hit = false, exhausted = false;

    const float b2_0 = b2[0];

    while (true) {
        if (!has && !exhausted) {
            int idx = atomicAdd(counter, 1);
            if (idx < NRAYS) {
                const float* r = rays + (size_t)idx * 6;
                ox = r[0]; oy = r[1]; oz = r[2];
                rdx = r[3]; rdy = r[4]; rdz = r[5];
                cd = NEARV; it = 0; hit = false; has = true; ridx = idx;
            } else {
                exhausted = true;
            }
        }
        if (__ballot(has) == 0ull) break;

        const float px = ox + rdx * cd;
        const float py = oy + rdy * cd;
        const float pz = oz + rdz * cd;

        const float d = sdf_eval(px, py, pz, W0, b0, W1, b1, W2, b2_0);

        if (has) {
            ++it;
            if (d < EPSV && cd <= FARV) hit = true;
            cd += d;
            if (hit || cd > FARV || it >= MAXIT) {
                t_out[ridx] = cd;
                hit_out[ridx] = hit ? 1 : 0;
                has = false;
            }
        }
    }
}

__global__ __launch_bounds__(256, 2)
void shade_kernel(const float* __restrict__ rays,
                  const float* __restrict__ W0, const float* __restrict__ b0,
                  const float* __restrict__ W1, const float* __restrict__ b1,
                  const float* __restrict__ W2, const float* __restrict__ b2,
                  const float* __restrict__ RW0, const float* __restrict__ Rb0,
                  const float* __restrict__ RW1, const float* __restrict__ Rb1,
                  const float* __restrict__ t_in, const int* __restrict__ hit_in,
                  float* __restrict__ out)
{
    __shared__ float sW0[3 * 64];
    __shared__ float sb0[64];
    __shared__ float sW1[64 * 64];
    __shared__ float sb1[64];
    __shared__ float sW2T[33 * 64];
    __shared__ float sb2[33];
    __shared__ float sRW0T[64 * 48];
    __shared__ float sRb0[64];
    __shared__ float sRW1[64 * 3];
    __shared__ float sRb1[3];

    const int tid = threadIdx.x;
    for (int i = tid; i < 3 * 64; i += 256) sW0[i] = W0[i];
    for (int i = tid; i < 64 * 64; i += 256) sW1[i] = W1[i];
    for (int i = tid; i < 33 * 64; i += 256) {
        const int c = i >> 6, j = i & 63;
        sW2T[i] = W2[j * 33 + c];
    }
    for (int i = tid; i < 64 * 41; i += 256) {
        const int u = i / 41, f = i - u * 41;
        sRW0T[u * 48 + f] = RW0[f * 64 + u];
    }
    if (tid < 64) { sb0[tid] = b0[tid]; sb1[tid] = b1[tid]; sRb0[tid] = Rb0[tid]; }
    if (tid < 33) sb2[tid] = b2[tid];
    if (tid < 192) sRW1[tid] = RW1[tid];
    if (tid < 3) sRb1[tid] = Rb1[tid];
    __syncthreads();

    const int i = blockIdx.x * 256 + tid;
    const bool hit = hit_in[i] != 0;

    if (__ballot(hit) == 0ull) {
        out[i * 3 + 0] = 0.f;
        out[i * 3 + 1] = 0.f;
        out[i * 3 + 2] = 0.f;
        return;
    }

    const float* r = rays + (size_t)i * 6;
    const float cd = t_in[i];
    const float ox = r[0], oy = r[1], oz = r[2];
    const float dx = r[3], dy = r[4], dz = r[5];
    const float px = ox + dx * cd;
    const float py = oy + dy * cd;
    const float pz = oz + dz * cd;

    float h1[64];
    #pragma unroll
    for (int j = 0; j < 64; ++j) h1[j] = 0.f;

    for (int k = 0; k < 64; ++k) {
        float z = px * sW0[k] + py * sW0[64 + k] + pz * sW0[128 + k];
        z += sb0[k];
        const float a = fmaxf(z, 0.f);
        #pragma unroll
        for (int j = 0; j < 64; ++j) h1[j] = fmaf(a, sW1[k * 64 + j], h1[j]);
    }
    #pragma unroll
    for (int j = 0; j < 64; ++j) h1[j] = fmaxf(h1[j] + sb1[j], 0.f);

    float lat[32];
    #pragma unroll
    for (int c = 1; c < 33; ++c) {
        float acc = 0.f;
        #pragma unroll
        for (int j = 0; j < 64; ++j) acc = fmaf(h1[j], sW2T[c * 64 + j], acc);
        lat[c - 1] = acc + sb2[c];
    }

    #pragma unroll
    for (int j = 0; j < 64; ++j) h1[j] = (h1[j] > 0.f) ? sW2T[j] : 0.f;

    float nx = 0.f, ny = 0.f, nz = 0.f;
    for (int k = 0; k < 64; ++k) {
        float z = px * sW0[k] + py * sW0[64 + k] + pz * sW0[128 + k];
        z += sb0[k];
        float g = 0.f;
        #pragma unroll
        for (int j = 0; j < 64; ++j) g = fmaf(h1[j], sW1[k * 64 + j], g);
        if (z > 0.f) {
            nx = fmaf(g, sW0[k], nx);
            ny = fmaf(g, sW0[64 + k], ny);
            nz = fmaf(g, sW0[128 + k], nz);
        }
    }
    if (!hit) { nx = 0.f; ny = 0.f; nz = 0.f; }

    float r0 = 0.f, r1 = 0.f, r2 = 0.f;
    for (int u = 0; u < 64; ++u) {
        const float* w = &sRW0T[u * 48];
        float a = px * w[0] + py * w[1] + pz * w[2];
        a = fmaf(dx, w[3], a); a = fmaf(dy, w[4], a); a = fmaf(dz, w[5], a);
        a = fmaf(nx, w[6], a); a = fmaf(ny, w[7], a); a = fmaf(nz, w[8], a);
        #pragma unroll
        for (int q = 0; q < 32; ++q) a = fmaf(lat[q], w[9 + q], a);
        a += sRb0[u];
        const float ru = fmaxf(a, 0.f);
        r0 = fmaf(ru, sRW1[u * 3 + 0], r0);
        r1 = fmaf(ru, sRW1[u * 3 + 1], r1);
        r2 = fmaf(ru, sRW1[u * 3 + 2], r2);
    }
    r0 += sRb1[0]; r1 += sRb1[1]; r2 += sRb1[2];

    const float o0 = 1.f / (1.f + expf(-r0));
    const float o1 = 1.f / (1.f + expf(-r1));
    const float o2 = 1.f / (1.f + expf(-r2));

    out[i * 3 + 0] = hit ? o0 : 0.f;
    out[i * 3 + 1] = hit ? o1 : 0.f;
    out[i * 3 + 2] = hit ? o2 : 0.f;
}

extern "C" void kernel_launch(void* const* d_in, const int* in_sizes, int n_in,
                              void* d_out, int out_size, void* d_ws, size_t ws_size,
                              hipStream_t stream) {
    const float* rays = (const float*)d_in[0];
    const float* W0   = (const float*)d_in[1];
    const float* b0   = (const float*)d_in[2];
    const float* W1   = (const float*)d_in[3];
    const float* b1   = (const float*)d_in[4];
    const float* W2   = (const float*)d_in[5];
    const float* b2   = (const float*)d_in[6];
    const float* RW0  = (const float*)d_in[7];
    const float* Rb0  = (const float*)d_in[8];
    const float* RW1  = (const float*)d_in[9];
    const float* Rb1  = (const float*)d_in[10];

    // Workspace layout (4-byte units):
    //   [0..31]                    counters: cnt[r]=survivors after round r (r<31), cnt[31]=hit count
    //   [32          .. 32+N)      t
    //   [32+N        .. 32+2N)     queue A idx
    //   [32+2N       .. 32+3N)     queue A cd
    //   [32+3N       .. 32+4N)     queue B idx
    //   [32+4N       .. 32+5N)     queue B cd
    //   [32+5N       .. 32+6N)     hit queue
    const size_t need = (size_t)(32 + 6 * NRAYS) * 4;

    if (ws_size >= need) {
        int*   cnt  = (int*)d_ws;
        float* t_ws = (float*)d_ws + 32;
        int*   qiA  = (int*)d_ws + 32 + (size_t)NRAYS;
        float* qcA  = (float*)d_ws + 32 + 2 * (size_t)NRAYS;
        int*   qiB  = (int*)d_ws + 32 + 3 * (size_t)NRAYS;
        float* qcB  = (float*)d_ws + 32 + 4 * (size_t)NRAYS;
        int*   hitq = (int*)d_ws + 32 + 5 * (size_t)NRAYS;

        hipMemsetAsync(cnt, 0, 32 * sizeof(int), stream);
        hipMemsetAsync(d_out, 0, (size_t)out_size, stream);

        // Chunk schedule: fine-grained while the death rate is high,
        // coarse for the creeper tail. Sums to MAXIT = 192.
        static const int sched[NROUNDS] =
            {1, 1, 2, 4, 8, 16, 16, 16, 16, 16, 16, 16, 16, 16, 16, 16};

        const int blocks = NRAYS / MBLK;
        int it_base = 0;

        // Round 0: all rays fresh, survivors -> queue A (cnt[0]).
        march_round<<<blocks, MBLK, 0, stream>>>(
            rays, W0, b0, W1, b1, W2, b2,
            1, it_base, sched[0], nullptr, nullptr, nullptr,
            &cnt[0], qiA, qcA, t_ws, hitq, &cnt[31]);
        it_base += sched[0];

        for (int r2 = 1; r2 < NROUNDS; ++r2) {
            const int*   icnt = &cnt[r2 - 1];
            int*         ocnt = &cnt[r2];
            const int*   ii = (r2 & 1) ? qiA : qiB;
            const float* ic = (r2 & 1) ? qcA : qcB;
            int*         oi = (r2 & 1) ? qiB : qiA;
            float*       oc = (r2 & 1) ? qcB : qcA;
            march_round<<<blocks, MBLK, 0, stream>>>(
                rays, W0, b0, W1, b1, W2, b2,
                0, it_base, sched[r2], icnt, ii, ic,
                ocnt, oi, oc, t_ws, hitq, &cnt[31]);
            it_base += sched[r2];
        }

        shade_hit<<<NRAYS / MBLK, MBLK, 0, stream>>>(
            rays, W0, b0, W1, b1, W2, b2, RW0, Rb0, RW1, Rb1,
            t_ws, hitq, &cnt[31], (float*)d_out);
    } else {
        // Fallback: previous passing path.
        float* t_ws  = (float*)d_ws;
        int*   hit_ws = (int*)d_ws + NRAYS;
        int*   ctr    = (int*)d_ws + 2 * NRAYS;

        hipMemsetAsync(ctr, 0, sizeof(int), stream);
        march_kernel<<<1024, 256, 0, stream>>>(rays, W0, b0, W1, b1, W2, b2,
                                               t_ws, hit_ws, ctr);
        shade_kernel<<<NRAYS / 256, 256, 0, stream>>>(rays, W0, b0, W1, b1, W2, b2,
                                                      RW0, Rb0, RW1, Rb1,
                                                      t_ws, hit_ws, (float*)d_out);
    }
}

// Round 13
// 3270.433 us; speedup vs baseline: 1.2702x; 1.0354x over previous
//
#include <hip/hip_runtime.h>
#include <math.h>

#define NRAYS 262144
#define MAXIT 192
#define NEARV 0.2f
#define FARV  2.0f
#define EPSV  0.001f
#define MBLK 256      // march block size (4 waves) — finer CU granularity for the tail
#define SBLK 512      // shade block size
#define NROUNDS 16    // schedule: 1,1,2,4,8 then 11x16 = 192 steps

// ---------------------------------------------------------------------------
// Single-ray SDF MLP eval (fallback path only) — canonical fma order,
// scalar weight loads.
// ---------------------------------------------------------------------------
__device__ __forceinline__ float sdf_eval(
    float px, float py, float pz,
    const float* __restrict__ W0, const float* __restrict__ b0,
    const float* __restrict__ W1, const float* __restrict__ b1,
    const float* __restrict__ W2, float b2_0)
{
    float h1[64];
    #pragma unroll
    for (int j = 0; j < 64; ++j) h1[j] = 0.f;

    for (int k = 0; k < 64; ++k) {
        float z = px * W0[k] + py * W0[64 + k] + pz * W0[128 + k];
        z += b0[k];
        const float a = fmaxf(z, 0.f);
        #pragma unroll
        for (int j = 0; j < 64; ++j) h1[j] = fmaf(a, W1[k * 64 + j], h1[j]);
    }

    float d = 0.f;
    #pragma unroll
    for (int j = 0; j < 64; ++j)
        d = fmaf(fmaxf(h1[j] + b1[j], 0.f), W2[j * 33], d);
    return d + b2_0;
}

// ---------------------------------------------------------------------------
// March kernel. R8 inner loop (66.7% busy, single-pass codegen) with:
//   - 256-thread blocks (R13 change): tail rounds with n survivors get
//     n/256 blocks instead of n/512 — all 256 CUs stay fed down to
//     n~65K, and R12's 36%-busy tail rounds (1 block/CU at n~130K)
//     regain residency. K$ working set = blocks/CU x 1KB phase window
//     + 1KB W0/b0 <= ~9KB, still K$-resident.
//   - (256,2): 256-reg unified budget, proven single-pass (R3: 44 VGPR,
//     R8: 48 VGPR). Budget-starved variants re-tile (+43% insts, R2/R6).
//   - raw s_barrier per 8 k's: phase-locks the block's waves into one K$
//     window (R6: busy 58.6->73.5%); no data crosses it, no waitcnt drain.
//   - kchunk argument: schedule 1,1,2,4,8,11x16 (R10).
// fma order identical to sdf_eval -> bit-identical t/hit.
// ---------------------------------------------------------------------------
__global__ __launch_bounds__(MBLK, 2)
void march_round(const float* __restrict__ rays,
                 const float* __restrict__ W0, const float* __restrict__ b0,
                 const float* __restrict__ W1, const float* __restrict__ b1,
                 const float* __restrict__ W2, const float* __restrict__ b2,
                 int round0, int it_base, int kchunk,
                 const int* __restrict__ in_cnt,
                 const int* __restrict__ in_idx, const float* __restrict__ in_cd,
                 int* __restrict__ out_cnt,
                 int* __restrict__ out_idx, float* __restrict__ out_cd,
                 float* __restrict__ t_out,
                 int* __restrict__ hitq, int* __restrict__ hit_cnt)
{
    const int i    = blockIdx.x * MBLK + threadIdx.x;
    const int lane = threadIdx.x & 63;
    const int n    = round0 ? NRAYS : *in_cnt;

    // Block-uniform early exit BEFORE any barrier (empty tail blocks).
    if (blockIdx.x * MBLK >= n) return;

    bool alive = (i < n);
    bool hit   = false;
    int  ridx  = 0;
    float cd   = NEARV;
    int  it    = it_base;

    if (alive) {
        if (round0) {
            ridx = i;
        } else {
            ridx = in_idx[i];
            cd   = in_cd[i];
        }
    }

    const float* r = rays + (size_t)ridx * 6;   // dead lanes read ray 0 (in-bounds)
    const float ox = r[0], oy = r[1], oz = r[2];
    const float rdx = r[3], rdy = r[4], rdz = r[5];
    const float b2_0 = b2[0];

    // Fixed trip count: every wave executes every barrier.
    for (int s = 0; s < kchunk; ++s) {
        const float px = ox + rdx * cd;
        const float py = oy + rdy * cd;
        const float pz = oz + rdz * cd;

        float h1[64];
        #pragma unroll
        for (int j = 0; j < 64; ++j) h1[j] = 0.f;

        for (int kt = 0; kt < 8; ++kt) {
            #pragma unroll
            for (int kk = 0; kk < 8; ++kk) {
                const int k = kt * 8 + kk;
                float z = px * W0[k] + py * W0[64 + k] + pz * W0[128 + k];
                z += b0[k];
                const float a = fmaxf(z, 0.f);
                #pragma unroll
                for (int j = 0; j < 64; ++j)
                    h1[j] = fmaf(a, W1[k * 64 + j], h1[j]);
            }
            // Phase clamp only (raw s_barrier, not __syncthreads).
            __builtin_amdgcn_s_barrier();
        }

        float d = 0.f;
        #pragma unroll
        for (int j = 0; j < 64; ++j)
            d = fmaf(fmaxf(h1[j] + b1[j], 0.f), W2[j * 33], d);
        d += b2_0;

        if (alive) {
            ++it;
            if (d < EPSV && cd <= FARV) hit = true;
            cd += d;
            if (hit || cd > FARV || it >= MAXIT) {
                t_out[ridx] = cd;
                if (hit) {
                    const int p = atomicAdd(hit_cnt, 1);
                    hitq[p] = ridx;
                }
                alive = false;
            }
        }
    }

    // Wave-aggregated compaction of survivors into the out-queue.
    const unsigned long long m = __ballot(alive);
    if (m != 0ull) {
        const int leader = __builtin_ctzll(m);
        int base = 0;
        if (lane == leader) base = atomicAdd(out_cnt, __builtin_popcountll(m));
        base = __shfl(base, leader);
        if (alive) {
            const int off = __builtin_popcountll(m & ((1ull << lane) - 1ull));
            out_idx[base + off] = ridx;
            out_cd[base + off]  = cd;
        }
    }
}

// ---------------------------------------------------------------------------
// Shade only the hit rays (dense hit queue). Output memset to zero.
// R12 version (verified: WRITE 324MB->6MB, no spill): ALL weights via the
// wave-uniform SCALAR path (zero LDS), (512,2) budget, s_barrier
// phase-lock on the two W1-streaming loops. Weight values and fma order
// are EXACTLY the passing kernel's (W2[j*33+c] == old sW2T[c*64+j],
// RW0[f*64+u] == old sRW0T[u*48+f]) -> bit-identical output.
// Dead lanes clamp qi -> hitq[0], compute garbage, skip the store (must
// exist for uniform barrier participation).
// ---------------------------------------------------------------------------
__global__ __launch_bounds__(SBLK, 2)
void shade_hit(const float* __restrict__ rays,
               const float* __restrict__ W0, const float* __restrict__ b0,
               const float* __restrict__ W1, const float* __restrict__ b1,
               const float* __restrict__ W2, const float* __restrict__ b2,
               const float* __restrict__ RW0, const float* __restrict__ Rb0,
               const float* __restrict__ RW1, const float* __restrict__ Rb1,
               const float* __restrict__ t_in,
               const int* __restrict__ hitq, const int* __restrict__ hit_cnt,
               float* __restrict__ out)
{
    const int n = *hit_cnt;
    if (blockIdx.x * SBLK >= n) return;   // block-uniform exit, pre-barrier

    const int qi    = blockIdx.x * SBLK + threadIdx.x;
    const bool valid = (qi < n);
    const int i     = hitq[valid ? qi : 0];   // dead lanes clamp to hitq[0]

    const float* r = rays + (size_t)i * 6;
    const float cd = t_in[i];
    const float ox = r[0], oy = r[1], oz = r[2];
    const float dx = r[3], dy = r[4], dz = r[5];
    const float px = ox + dx * cd;
    const float py = oy + dy * cd;
    const float pz = oz + dz * cd;

    // ---- forward, layer 1 accumulation (scalar weights, phase-locked) ----
    float h1[64];
    #pragma unroll
    for (int j = 0; j < 64; ++j) h1[j] = 0.f;

    for (int kt = 0; kt < 8; ++kt) {
        #pragma unroll
        for (int kk = 0; kk < 8; ++kk) {
            const int k = kt * 8 + kk;
            float z = px * W0[k] + py * W0[64 + k] + pz * W0[128 + k];
            z += b0[k];
            const float a = fmaxf(z, 0.f);
            #pragma unroll
            for (int j = 0; j < 64; ++j) h1[j] = fmaf(a, W1[k * 64 + j], h1[j]);
        }
        __builtin_amdgcn_s_barrier();   // phase clamp only
    }
    #pragma unroll
    for (int j = 0; j < 64; ++j) h1[j] = fmaxf(h1[j] + b1[j], 0.f);

    // ---- latent = out[:,1:33]  (W2[j*33+c] == old sW2T[c*64+j]) ----
    float lat[32];
    #pragma unroll
    for (int c = 1; c < 33; ++c) {
        float acc = 0.f;
        #pragma unroll
        for (int j = 0; j < 64; ++j) acc = fmaf(h1[j], W2[j * 33 + c], acc);
        lat[c - 1] = acc + b2[c];
    }

    // ---- backward: gz1 = (z1>0) ? W2[:,0] : 0 ----
    #pragma unroll
    for (int j = 0; j < 64; ++j) h1[j] = (h1[j] > 0.f) ? W2[j * 33] : 0.f;

    float nx = 0.f, ny = 0.f, nz = 0.f;
    for (int kt = 0; kt < 8; ++kt) {
        #pragma unroll
        for (int kk = 0; kk < 8; ++kk) {
            const int k = kt * 8 + kk;
            float z = px * W0[k] + py * W0[64 + k] + pz * W0[128 + k];
            z += b0[k];
            float g = 0.f;
            #pragma unroll
            for (int j = 0; j < 64; ++j) g = fmaf(h1[j], W1[k * 64 + j], g);
            if (z > 0.f) {
                nx = fmaf(g, W0[k], nx);
                ny = fmaf(g, W0[64 + k], ny);
                nz = fmaf(g, W0[128 + k], nz);
            }
        }
        __builtin_amdgcn_s_barrier();   // phase clamp only
    }

    // ---- render MLP  (RW0[f*64+u] == old sRW0T[u*48+f]) ----
    float r0 = 0.f, r1 = 0.f, r2 = 0.f;
    for (int u = 0; u < 64; ++u) {
        float a = px * RW0[u] + py * RW0[64 + u] + pz * RW0[128 + u];
        a = fmaf(dx, RW0[3 * 64 + u], a);
        a = fmaf(dy, RW0[4 * 64 + u], a);
        a = fmaf(dz, RW0[5 * 64 + u], a);
        a = fmaf(nx, RW0[6 * 64 + u], a);
        a = fmaf(ny, RW0[7 * 64 + u], a);
        a = fmaf(nz, RW0[8 * 64 + u], a);
        #pragma unroll
        for (int q = 0; q < 32; ++q) a = fmaf(lat[q], RW0[(9 + q) * 64 + u], a);
        a += Rb0[u];
        const float ru = fmaxf(a, 0.f);
        r0 = fmaf(ru, RW1[u * 3 + 0], r0);
        r1 = fmaf(ru, RW1[u * 3 + 1], r1);
        r2 = fmaf(ru, RW1[u * 3 + 2], r2);
    }
    r0 += Rb1[0]; r1 += Rb1[1]; r2 += Rb1[2];

    if (valid) {
        out[i * 3 + 0] = 1.f / (1.f + expf(-r0));
        out[i * 3 + 1] = 1.f / (1.f + expf(-r1));
        out[i * 3 + 2] = 1.f / (1.f + expf(-r2));
    }
}

// ---------------------------------------------------------------------------
// Fallback path (only if workspace is too small for the queues).
// ---------------------------------------------------------------------------
__global__ __launch_bounds__(256, 2)
void march_kernel(const float* __restrict__ rays,
                  const float* __restrict__ W0, const float* __restrict__ b0,
                  const float* __restrict__ W1, const float* __restrict__ b1,
                  const float* __restrict__ W2, const float* __restrict__ b2,
                  float* __restrict__ t_out, int* __restrict__ hit_out,
                  int* __restrict__ counter)
{
    float ox = 0.f, oy = 0.f, oz = 0.f, rdx = 0.f, rdy = 0.f, rdz = 0.f;
    float cd = 0.f;
    int ridx = -1, it = 0;
    bool has = false, hit = false, exhausted = false;

    const float b2_0 = b2[0];

    while (true) {
        if (!has && !exhausted) {
            int idx = atomicAdd(counter, 1);
            if (idx < NRAYS) {
                const float* r = rays + (size_t)idx * 6;
                ox = r[0]; oy = r[1]; oz = r[2];
                rdx = r[3]; rdy = r[4]; rdz = r[5];
                cd = NEARV; it = 0; hit = false; has = true; ridx = idx;
            } else {
                exhausted = true;
            }
        }
        if (__ballot(has) == 0ull) break;

        const float px = ox + rdx * cd;
        const float py = oy + rdy * cd;
        const float pz = oz + rdz * cd;

        const float d = sdf_eval(px, py, pz, W0, b0, W1, b1, W2, b2_0);

        if (has) {
            ++it;
            if (d < EPSV && cd <= FARV) hit = true;
            cd += d;
            if (hit || cd > FARV || it >= MAXIT) {
                t_out[ridx] = cd;
                hit_out[ridx] = hit ? 1 : 0;
                has = false;
            }
        }
    }
}

__global__ __launch_bounds__(256, 2)
void shade_kernel(const float* __restrict__ rays,
                  const float* __restrict__ W0, const float* __restrict__ b0,
                  const float* __restrict__ W1, const float* __restrict__ b1,
                  const float* __restrict__ W2, const float* __restrict__ b2,
                  const float* __restrict__ RW0, const float* __restrict__ Rb0,
                  const float* __restrict__ RW1, const float* __restrict__ Rb1,
                  const float* __restrict__ t_in, const int* __restrict__ hit_in,
                  float* __restrict__ out)
{
    __shared__ float sW0[3 * 64];
    __shared__ float sb0[64];
    __shared__ float sW1[64 * 64];
    __shared__ float sb1[64];
    __shared__ float sW2T[33 * 64];
    __shared__ float sb2[33];
    __shared__ float sRW0T[64 * 48];
    __shared__ float sRb0[64];
    __shared__ float sRW1[64 * 3];
    __shared__ float sRb1[3];

    const int tid = threadIdx.x;
    for (int i = tid; i < 3 * 64; i += 256) sW0[i] = W0[i];
    for (int i = tid; i < 64 * 64; i += 256) sW1[i] = W1[i];
    for (int i = tid; i < 33 * 64; i += 256) {
        const int c = i >> 6, j = i & 63;
        sW2T[i] = W2[j * 33 + c];
    }
    for (int i = tid; i < 64 * 41; i += 256) {
        const int u = i / 41, f = i - u * 41;
        sRW0T[u * 48 + f] = RW0[f * 64 + u];
    }
    if (tid < 64) { sb0[tid] = b0[tid]; sb1[tid] = b1[tid]; sRb0[tid] = Rb0[tid]; }
    if (tid < 33) sb2[tid] = b2[tid];
    if (tid < 192) sRW1[tid] = RW1[tid];
    if (tid < 3) sRb1[tid] = Rb1[tid];
    __syncthreads();

    const int i = blockIdx.x * 256 + tid;
    const bool hit = hit_in[i] != 0;

    if (__ballot(hit) == 0ull) {
        out[i * 3 + 0] = 0.f;
        out[i * 3 + 1] = 0.f;
        out[i * 3 + 2] = 0.f;
        return;
    }

    const float* r = rays + (size_t)i * 6;
    const float cd = t_in[i];
    const float ox = r[0], oy = r[1], oz = r[2];
    const float dx = r[3], dy = r[4], dz = r[5];
    const float px = ox + dx * cd;
    const float py = oy + dy * cd;
    const float pz = oz + dz * cd;

    float h1[64];
    #pragma unroll
    for (int j = 0; j < 64; ++j) h1[j] = 0.f;

    for (int k = 0; k < 64; ++k) {
        float z = px * sW0[k] + py * sW0[64 + k] + pz * sW0[128 + k];
        z += sb0[k];
        const float a = fmaxf(z, 0.f);
        #pragma unroll
        for (int j = 0; j < 64; ++j) h1[j] = fmaf(a, sW1[k * 64 + j], h1[j]);
    }
    #pragma unroll
    for (int j = 0; j < 64; ++j) h1[j] = fmaxf(h1[j] + sb1[j], 0.f);

    float lat[32];
    #pragma unroll
    for (int c = 1; c < 33; ++c) {
        float acc = 0.f;
        #pragma unroll
        for (int j = 0; j < 64; ++j) acc = fmaf(h1[j], sW2T[c * 64 + j], acc);
        lat[c - 1] = acc + sb2[c];
    }

    #pragma unroll
    for (int j = 0; j < 64; ++j) h1[j] = (h1[j] > 0.f) ? sW2T[j] : 0.f;

    float nx = 0.f, ny = 0.f, nz = 0.f;
    for (int k = 0; k < 64; ++k) {
        float z = px * sW0[k] + py * sW0[64 + k] + pz * sW0[128 + k];
        z += sb0[k];
        float g = 0.f;
        #pragma unroll
        for (int j = 0; j < 64; ++j) g = fmaf(h1[j], sW1[k * 64 + j], g);
        if (z > 0.f) {
            nx = fmaf(g, sW0[k], nx);
            ny = fmaf(g, sW0[64 + k], ny);
            nz = fmaf(g, sW0[128 + k], nz);
        }
    }
    if (!hit) { nx = 0.f; ny = 0.f; nz = 0.f; }

    float r0 = 0.f, r1 = 0.f, r2 = 0.f;
    for (int u = 0; u < 64; ++u) {
        const float* w = &sRW0T[u * 48];
        float a = px * w[0] + py * w[1] + pz * w[2];
        a = fmaf(dx, w[3], a); a = fmaf(dy, w[4], a); a = fmaf(dz, w[5], a);
        a = fmaf(nx, w[6], a); a = fmaf(ny, w[7], a); a = fmaf(nz, w[8], a);
        #pragma unroll
        for (int q = 0; q < 32; ++q) a = fmaf(lat[q], w[9 + q], a);
        a += sRb0[u];
        const float ru = fmaxf(a, 0.f);
        r0 = fmaf(ru, sRW1[u * 3 + 0], r0);
        r1 = fmaf(ru, sRW1[u * 3 + 1], r1);
        r2 = fmaf(ru, sRW1[u * 3 + 2], r2);
    }
    r0 += sRb1[0]; r1 += sRb1[1]; r2 += sRb1[2];

    const float o0 = 1.f / (1.f + expf(-r0));
    const float o1 = 1.f / (1.f + expf(-r1));
    const float o2 = 1.f / (1.f + expf(-r2));

    out[i * 3 + 0] = hit ? o0 : 0.f;
    out[i * 3 + 1] = hit ? o1 : 0.f;
    out[i * 3 + 2] = hit ? o2 : 0.f;
}

extern "C" void kernel_launch(void* const* d_in, const int* in_sizes, int n_in,
                              void* d_out, int out_size, void* d_ws, size_t ws_size,
                              hipStream_t stream) {
    const float* rays = (const float*)d_in[0];
    const float* W0   = (const float*)d_in[1];
    const float* b0   = (const float*)d_in[2];
    const float* W1   = (const float*)d_in[3];
    const float* b1   = (const float*)d_in[4];
    const float* W2   = (const float*)d_in[5];
    const float* b2   = (const float*)d_in[6];
    const float* RW0  = (const float*)d_in[7];
    const float* Rb0  = (const float*)d_in[8];
    const float* RW1  = (const float*)d_in[9];
    const float* Rb1  = (const float*)d_in[10];

    // Workspace layout (4-byte units):
    //   [0..31]                    counters: cnt[r]=survivors after round r (r<31), cnt[31]=hit count
    //   [32          .. 32+N)      t
    //   [32+N        .. 32+2N)     queue A idx
    //   [32+2N       .. 32+3N)     queue A cd
    //   [32+3N       .. 32+4N)     queue B idx
    //   [32+4N       .. 32+5N)     queue B cd
    //   [32+5N       .. 32+6N)     hit queue
    const size_t need = (size_t)(32 + 6 * NRAYS) * 4;

    if (ws_size >= need) {
        int*   cnt  = (int*)d_ws;
        float* t_ws = (float*)d_ws + 32;
        int*   qiA  = (int*)d_ws + 32 + (size_t)NRAYS;
        float* qcA  = (float*)d_ws + 32 + 2 * (size_t)NRAYS;
        int*   qiB  = (int*)d_ws + 32 + 3 * (size_t)NRAYS;
        float* qcB  = (float*)d_ws + 32 + 4 * (size_t)NRAYS;
        int*   hitq = (int*)d_ws + 32 + 5 * (size_t)NRAYS;

        hipMemsetAsync(cnt, 0, 32 * sizeof(int), stream);
        hipMemsetAsync(d_out, 0, (size_t)out_size, stream);

        // Chunk schedule: fine-grained while the death rate is high,
        // coarse for the creeper tail. Sums to MAXIT = 192.
        static const int sched[NROUNDS] =
            {1, 1, 2, 4, 8, 16, 16, 16, 16, 16, 16, 16, 16, 16, 16, 16};

        const int blocks = NRAYS / MBLK;
        int it_base = 0;

        // Round 0: all rays fresh, survivors -> queue A (cnt[0]).
        march_round<<<blocks, MBLK, 0, stream>>>(
            rays, W0, b0, W1, b1, W2, b2,
            1, it_base, sched[0], nullptr, nullptr, nullptr,
            &cnt[0], qiA, qcA, t_ws, hitq, &cnt[31]);
        it_base += sched[0];

        for (int r2 = 1; r2 < NROUNDS; ++r2) {
            const int*   icnt = &cnt[r2 - 1];
            int*         ocnt = &cnt[r2];
            const int*   ii = (r2 & 1) ? qiA : qiB;
            const float* ic = (r2 & 1) ? qcA : qcB;
            int*         oi = (r2 & 1) ? qiB : qiA;
            float*       oc = (r2 & 1) ? qcB : qcA;
            march_round<<<blocks, MBLK, 0, stream>>>(
                rays, W0, b0, W1, b1, W2, b2,
                0, it_base, sched[r2], icnt, ii, ic,
                ocnt, oi, oc, t_ws, hitq, &cnt[31]);
            it_base += sched[r2];
        }

        shade_hit<<<NRAYS / SBLK, SBLK, 0, stream>>>(
            rays, W0, b0, W1, b1, W2, b2, RW0, Rb0, RW1, Rb1,
            t_ws, hitq, &cnt[31], (float*)d_out);
    } else {
        // Fallback: previous passing path.
        float* t_ws  = (float*)d_ws;
        int*   hit_ws = (int*)d_ws + NRAYS;
        int*   ctr    = (int*)d_ws + 2 * NRAYS;

        hipMemsetAsync(ctr, 0, sizeof(int), stream);
        march_kernel<<<1024, 256, 0, stream>>>(rays, W0, b0, W1, b1, W2, b2,
                                               t_ws, hit_ws, ctr);
        shade_kernel<<<NRAYS / 256, 256, 0, stream>>>(rays, W0, b0, W1, b1, W2, b2,
                                                      RW0, Rb0, RW1, Rb1,
                                                      t_ws, hit_ws, (float*)d_out);
    }
}